// Round 17
// baseline (2545.316 us; speedup 1.0000x reference)
//
#include <hip/hip_runtime.h>
#include <hip/hip_bf16.h>
#include <math.h>

#define B_     8
#define IMG_   224
#define PATCH_ 16
#define CIN_   3
#define D_     768
#define NH_    12
#define DEPTH_ 12
#define NE_    8
#define NCLS_  1000
#define DH_    3072
#define HD_    64
#define GRD_   14
#define NPAT_  196
#define NTOK_  197
#define T_     (B_*NTOK_)    /* 1576 tokens */
#define TP_    (B_*NPAT_)    /* 1568 patches */
#define NSLOT_ (T_*2)        /* 3152 (token,slot) pairs */

typedef __bf16 bf16_t;
typedef __bf16 bf16x8 __attribute__((ext_vector_type(8)));
typedef __bf16 bf16x4 __attribute__((ext_vector_type(4)));
typedef float  f32x4  __attribute__((ext_vector_type(4)));

static __device__ __forceinline__ float gelu_f(float x){
    return 0.5f * x * (1.0f + erff(x * 0.70710678118654752440f));
}

// ---------------- f32 -> bf16 bulk convert (8 elems/thread) ------------------
__global__ __launch_bounds__(256) void k_cvt(const float* __restrict__ in,
                                             bf16_t* __restrict__ out, int n){
    int i = (blockIdx.x*256 + threadIdx.x)*8;
    if (i >= n) return;
    float4 a = *reinterpret_cast<const float4*>(in + i);
    float4 b = *reinterpret_cast<const float4*>(in + i + 4);
    bf16x8 h;
    h[0]=(bf16_t)a.x; h[1]=(bf16_t)a.y; h[2]=(bf16_t)a.z; h[3]=(bf16_t)a.w;
    h[4]=(bf16_t)b.x; h[5]=(bf16_t)b.y; h[6]=(bf16_t)b.z; h[7]=(bf16_t)b.w;
    *reinterpret_cast<bf16x8*>(out + i) = h;
}

// ---------------- patch gather: x[B,3,224,224] -> pbuf[1568,768] bf16 -------
__global__ void k_patch_gather(const float* __restrict__ x, bf16_t* __restrict__ pbuf){
    int idx = blockIdx.x*256 + threadIdx.x;
    if (idx >= TP_*D_) return;
    int k  = idx % D_;
    int tp = idx / D_;
    int p  = tp % NPAT_, b = tp / NPAT_;
    int c  = k >> 8;
    int ij = k & 255;
    int i  = ij >> 4, j = ij & 15;
    int gi = p / GRD_, gj = p % GRD_;
    pbuf[idx] = (bf16_t)x[(((size_t)b*CIN_ + c)*IMG_ + gi*PATCH_ + i)*IMG_ + gj*PATCH_ + j];
}

// ---------------- unified bf16 MFMA GEMM: BK=128 single buffer ---------------
// BM=64, BN=128, BK=128, 256 threads (4 waves x 32x64 output), 48KB LDS
// (single buffer) -> 3 blk/CU. Validated r16 on dense (grid-limited: halves
// the serial K-chain's drain count); extended here to MOE/GATHER (occupancy
// regime: halves barrier count at identical occupancy). Swizzle: 16 chunks
// of 8 bf16 per row; lds chunk lc = global chunk lc^(row&7); frag read chunk
// c at c^(row&7). Row stride 256B -> same 2-way bank pattern.
// PARTIAL=1: raw f32 out (no bias/act) [+ ksid*M*N when KSPLIT=2].
template<int ACT, int GATHER, int MOE, int OUTBF, int KSPLIT, int PARTIAL>
__global__ __launch_bounds__(256) void k_dgemm(
    const bf16_t* __restrict__ A, const int* __restrict__ gidx,
    const bf16_t* __restrict__ W, const float* __restrict__ bias,
    void* __restrict__ Cout, int M, int N, int K,
    const int* __restrict__ moff, const int* __restrict__ mcnt)
{
    __shared__ __align__(16) bf16_t As[64*128];
    __shared__ __align__(16) bf16_t Bs[128*128];
    const int tid = threadIdx.x, lane = tid & 63, w = tid >> 6;
    int row_begin, Mhi, ksid;
    if (MOE) {
        const int e = blockIdx.z;
        const int o = moff[e], c = mcnt[e];
        const int rb = (KSPLIT == 2) ? (int)(blockIdx.y >> 1) : (int)blockIdx.y;
        ksid = (KSPLIT == 2) ? (int)(blockIdx.y & 1) : 0;
        row_begin = o + rb*64;
        Mhi = o + c;
        if (row_begin >= Mhi) return;
        W += (size_t)e*N*K;
        if (!PARTIAL) bias += (size_t)e*N;
    } else {
        row_begin = blockIdx.y*64;
        ksid = (KSPLIT == 2) ? (int)blockIdx.z : 0;
        Mhi = M;
    }
    const int bn = blockIdx.x*128;
    const int KL = K / KSPLIT;

    // staging: 4 rows per wave-load (lane>>4 row-in-segment, lane&15 chunk)
    // A: 16 segments of 4 rows -> 4 per wave; B: 32 segments -> 8 per wave
    const bf16_t* aG[4];
    int aOff[4];
    #pragma unroll
    for (int i = 0; i < 4; ++i) {
        const int s = w*4 + i;
        const int row_l = s*4 + (lane >> 4);
        const int cc = (lane & 15) ^ (row_l & 7);
        const int gg = min(row_begin + row_l, Mhi - 1);
        const int tok = GATHER ? (gidx[gg] >> 1) : gg;
        aG[i] = A + (size_t)tok*K + ksid*KL + cc*8;
        aOff[i] = s*512;
    }
    const bf16_t* wG[8];
    int wOff[8];
    #pragma unroll
    for (int j = 0; j < 8; ++j) {
        const int s = w*8 + j;
        const int row_l = s*4 + (lane >> 4);
        const int cc = (lane & 15) ^ (row_l & 7);
        wG[j] = W + (size_t)(bn + row_l)*K + ksid*KL + cc*8;
        wOff[j] = s*512;
    }
    // frag read byte offsets: row stride 256B; chunk c = ks*4+kg, ks in [0,4)
    const int wm = (w >> 1)*32, wn = (w & 1)*64;
    const int fr = lane & 15, kg = lane >> 4;
    int offA[4][2], offB[4][4];
    #pragma unroll
    for (int ks = 0; ks < 4; ++ks) {
        #pragma unroll
        for (int t = 0; t < 2; ++t) {
            const int ra = wm + t*16 + fr;
            offA[ks][t] = ra*256 + (((ks*4 + kg) ^ (ra & 7)) << 4);
        }
        #pragma unroll
        for (int t = 0; t < 4; ++t) {
            const int rb2 = wn + t*16 + fr;
            offB[ks][t] = rb2*256 + (((ks*4 + kg) ^ (rb2 & 7)) << 4);
        }
    }

    f32x4 acc[2][4] = {};
    const int nt = KL >> 7;
    for (int t = 0; t < nt; ++t) {
        if (t) __syncthreads();            // prior reads of As/Bs complete
        #pragma unroll
        for (int i = 0; i < 4; ++i) {
            __builtin_amdgcn_global_load_lds(
                (const __attribute__((address_space(1))) void*)(aG[i]),
                (__attribute__((address_space(3))) void*)(&As[aOff[i]]), 16, 0, 0);
            aG[i] += 128;
        }
        #pragma unroll
        for (int j = 0; j < 8; ++j) {
            __builtin_amdgcn_global_load_lds(
                (const __attribute__((address_space(1))) void*)(wG[j]),
                (__attribute__((address_space(3))) void*)(&Bs[wOff[j]]), 16, 0, 0);
            wG[j] += 128;
        }
        __syncthreads();                   // drains vmcnt -> tile ready
        const char* baseA = (const char*)&As[0];
        const char* baseB = (const char*)&Bs[0];
        #pragma unroll
        for (int ks = 0; ks < 4; ++ks) {
            bf16x8 af[2], bf[4];
            #pragma unroll
            for (int t2 = 0; t2 < 2; ++t2)
                af[t2] = *reinterpret_cast<const bf16x8*>(baseA + offA[ks][t2]);
            #pragma unroll
            for (int t2 = 0; t2 < 4; ++t2)
                bf[t2] = *reinterpret_cast<const bf16x8*>(baseB + offB[ks][t2]);
            #pragma unroll
            for (int mt = 0; mt < 2; ++mt)
                #pragma unroll
                for (int nt2 = 0; nt2 < 4; ++nt2)
                    acc[mt][nt2] = __builtin_amdgcn_mfma_f32_16x16x32_bf16(
                        af[mt], bf[nt2], acc[mt][nt2], 0, 0, 0);
        }
    }
    float*  Cf = (float*)Cout + ((PARTIAL && KSPLIT == 2) ? (size_t)ksid*M*N : (size_t)0);
    bf16_t* Cb = (bf16_t*)Cout;
    const int cr = kg*4;
    #pragma unroll
    for (int nt2 = 0; nt2 < 4; ++nt2) {
        const int n = bn + wn + nt2*16 + fr;
        const float bv = PARTIAL ? 0.0f : bias[n];
        #pragma unroll
        for (int mt = 0; mt < 2; ++mt) {
            #pragma unroll
            for (int r2 = 0; r2 < 4; ++r2) {
                const int m = row_begin + wm + mt*16 + cr + r2;
                if (m < Mhi) {
                    float v = acc[mt][nt2][r2] + bv;
                    if (ACT) v = gelu_f(v);
                    if (OUTBF) Cb[(size_t)m*N + n] = (bf16_t)v;
                    else       Cf[(size_t)m*N + n] = v;
                }
            }
        }
    }
}

// ---------------- LN core (device) -------------------------------------------
struct LNOut { float y0, y1, y2; };
static __device__ __forceinline__ LNOut ln_block(float v0, float v1, float v2,
        const float* __restrict__ w, const float* __restrict__ b,
        float* red, int tid)
{
    const int wid = tid >> 6, lane = tid & 63;
    float s = v0 + v1 + v2;
    for (int m=32;m>0;m>>=1) s += __shfl_xor(s, m);
    if (lane == 0) red[wid] = s;
    __syncthreads();
    if (tid == 0) red[4] = (red[0]+red[1]+red[2]+red[3]) * (1.0f/768.0f);
    __syncthreads();
    const float mean = red[4];
    float d0 = v0-mean, d1 = v1-mean, d2 = v2-mean;
    float q = d0*d0 + d1*d1 + d2*d2;
    for (int m=32;m>0;m>>=1) q += __shfl_xor(q, m);
    if (lane == 0) red[wid] = q;
    __syncthreads();
    if (tid == 0) {
        float var = (red[0]+red[1]+red[2]+red[3]) * (1.0f/768.0f);
        red[5] = 1.0f / sqrtf(var + 1e-5f);
    }
    __syncthreads();
    const float rstd = red[5];
    LNOut o;
    o.y0 = d0*rstd*w[tid    ] + b[tid    ];
    o.y1 = d1*rstd*w[tid+256] + b[tid+256];
    o.y2 = d2*rstd*w[tid+512] + b[tid+512];
    return o;
}

// ---------------- plain LayerNorm (final) ------------------------------------
template<typename TOUT>
__global__ __launch_bounds__(256) void k_ln(const float* __restrict__ X,
        const float* __restrict__ w, const float* __restrict__ b,
        TOUT* __restrict__ Y, int in_mul)
{
    __shared__ float red[8];
    const int r = blockIdx.x, tid = threadIdx.x;
    const float* xr = X + (size_t)r*in_mul*D_;
    LNOut o = ln_block(xr[tid], xr[tid+256], xr[tid+512], w, b, red, tid);
    TOUT* yr = Y + (size_t)r*D_;
    yr[tid] = (TOUT)o.y0; yr[tid+256] = (TOUT)o.y1; yr[tid+512] = (TOUT)o.y2;
}

// ---------------- assemble (cls/patch + pos) + LN1 of layer 0 ----------------
__global__ __launch_bounds__(256) void k_asmln(const float* __restrict__ pe,
        const float* __restrict__ cls, const float* __restrict__ pos,
        float* __restrict__ z, const float* __restrict__ w,
        const float* __restrict__ b, bf16_t* __restrict__ Y)
{
    __shared__ float red[8];
    const int t = blockIdx.x, tid = threadIdx.x;
    const int bb = t / NTOK_, r = t % NTOK_;
    float v[3];
    #pragma unroll
    for (int j = 0; j < 3; ++j) {
        const int n = tid + j*256;
        if (r == 0) v[j] = cls[n] + pos[n];
        else        v[j] = pe[((size_t)bb*NPAT_ + (r-1))*D_ + n] + pos[(size_t)r*D_ + n];
        z[(size_t)t*D_ + n] = v[j];
    }
    LNOut o = ln_block(v[0], v[1], v[2], w, b, red, tid);
    bf16_t* yr = Y + (size_t)t*D_;
    yr[tid] = (bf16_t)o.y0; yr[tid+256] = (bf16_t)o.y1; yr[tid+512] = (bf16_t)o.y2;
}

// -------- z += P0(+P1)+bias; LN -> Y; optional MoE gate ----------------------
template<int GATE, int NP>
__global__ __launch_bounds__(256) void k_addln(
    float* __restrict__ z, const float* __restrict__ P,
    const float* __restrict__ bias,
    const float* __restrict__ w, const float* __restrict__ b,
    bf16_t* __restrict__ Y,
    const float* __restrict__ gw, const float* __restrict__ gb,
    int* __restrict__ t_e, float* __restrict__ t_sc)
{
    __shared__ float red[8];
    __shared__ float red2[4][8];
    const int t = blockIdx.x, tid = threadIdx.x;
    const int wid = tid >> 6, lane = tid & 63;
    const float* P1 = P + (size_t)T_*D_;
    float v[3];
    #pragma unroll
    for (int j = 0; j < 3; ++j) {
        const int n = tid + j*256;
        float nv = z[(size_t)t*D_+n] + P[(size_t)t*D_+n] + bias[n];
        if (NP == 2) nv += P1[(size_t)t*D_+n];
        z[(size_t)t*D_+n] = nv;
        v[j] = nv;
    }
    LNOut o = ln_block(v[0], v[1], v[2], w, b, red, tid);
    bf16_t* yr = Y + (size_t)t*D_;
    yr[tid] = (bf16_t)o.y0; yr[tid+256] = (bf16_t)o.y1; yr[tid+512] = (bf16_t)o.y2;
    if (GATE) {
        float p[NE_];
        #pragma unroll
        for (int e = 0; e < NE_; ++e)
            p[e] = o.y0*gw[e*D_+tid] + o.y1*gw[e*D_+tid+256] + o.y2*gw[e*D_+tid+512];
        #pragma unroll
        for (int e = 0; e < NE_; ++e)
            for (int m=32;m>0;m>>=1) p[e] += __shfl_xor(p[e], m);
        if (lane == 0)
            #pragma unroll
            for (int e = 0; e < NE_; ++e) red2[wid][e] = p[e];
        __syncthreads();
        if (tid == 0) {
            float l[NE_];
            #pragma unroll
            for (int e = 0; e < NE_; ++e)
                l[e] = red2[0][e]+red2[1][e]+red2[2][e]+red2[3][e] + gb[e];
            int i0 = 0;
            for (int e = 1; e < NE_; ++e) if (l[e] > l[i0]) i0 = e;
            int i1 = -1;
            for (int e = 0; e < NE_; ++e) if (e != i0 && (i1 < 0 || l[e] > l[i1])) i1 = e;
            float e1 = __expf(l[i1] - l[i0]);
            float s = 1.0f + e1;
            t_e[t*2]   = i0;   t_e[t*2+1]  = i1;
            t_sc[t*2]  = 1.0f/s; t_sc[t*2+1] = e1/s;
        }
    }
}

// ---------------- scan+scatter: one block ------------------------------------
__global__ __launch_bounds__(1024) void k_scansc(const int* __restrict__ t_e,
        int* __restrict__ gidx, int* __restrict__ rg,
        int* __restrict__ offs, int* __restrict__ counts)
{
    __shared__ int h[NE_], o[NE_], c2[NE_];
    const int tid = threadIdx.x;
    if (tid < NE_) h[tid] = 0;
    __syncthreads();
    for (int id = tid; id < NSLOT_; id += 1024) atomicAdd(&h[t_e[id]], 1);
    __syncthreads();
    if (tid == 0) {
        int s = 0;
        for (int e = 0; e < NE_; ++e) { o[e] = s; s += h[e]; c2[e] = 0; }
    }
    __syncthreads();
    if (tid < NE_) { offs[tid] = o[tid]; counts[tid] = h[tid]; }
    for (int id = tid; id < NSLOT_; id += 1024) {
        int e = t_e[id];
        int pos = atomicAdd(&c2[e], 1);
        int g = o[e] + pos;
        gidx[g] = id;
        rg[id] = g;
    }
}

// -------- MoE combine from 2 partials (+expert bias); optional next-LN -------
template<int LN>
__global__ __launch_bounds__(256) void k_comb(
    const float* __restrict__ mp, const float* __restrict__ b2,
    const int* __restrict__ t_e, const int* __restrict__ rg,
    const float* __restrict__ t_sc, float* __restrict__ z,
    const float* __restrict__ w, const float* __restrict__ b,
    bf16_t* __restrict__ Y)
{
    __shared__ float red[8];
    const int t = blockIdx.x, tid = threadIdx.x;
    const int g0 = rg[2*t], g1 = rg[2*t+1];
    const int e0 = t_e[2*t], e1 = t_e[2*t+1];
    const float s0 = t_sc[2*t], s1 = t_sc[2*t+1];
    const float* mp1 = mp + (size_t)NSLOT_*D_;
    float v[3];
    #pragma unroll
    for (int j = 0; j < 3; ++j) {
        const int n = tid + j*256;
        float y0 = mp[(size_t)g0*D_+n] + mp1[(size_t)g0*D_+n] + b2[(size_t)e0*D_+n];
        float y1 = mp[(size_t)g1*D_+n] + mp1[(size_t)g1*D_+n] + b2[(size_t)e1*D_+n];
        float nv = z[(size_t)t*D_+n] + s0*y0 + s1*y1;
        z[(size_t)t*D_+n] = nv;
        v[j] = nv;
    }
    if (LN) {
        LNOut o = ln_block(v[0], v[1], v[2], w, b, red, tid);
        bf16_t* yr = Y + (size_t)t*D_;
        yr[tid] = (bf16_t)o.y0; yr[tid+256] = (bf16_t)o.y1; yr[tid+512] = (bf16_t)o.y2;
    }
}

// ---------------- attention: wave-per-2-queries, barrier-free ----------------
__global__ __launch_bounds__(256) void k_attn(const bf16_t* __restrict__ qkv,
                                              bf16_t* __restrict__ out)
{
    __shared__ bf16_t Kl[NTOK_*68];
    __shared__ float  qs[8][64];
    __shared__ bf16_t ps[8][200];
    const int qb = blockIdx.x*8;
    const int h = blockIdx.y, b = blockIdx.z;
    const int tid = threadIdx.x, lane = tid & 63, wid = tid >> 6;
    for (int id = tid; id < NTOK_*8; id += 256) {
        const int m = id >> 3, c = id & 7;
        bf16x8 v = *reinterpret_cast<const bf16x8*>(
            qkv + (size_t)(b*NTOK_+m)*2304 + 768 + h*HD_ + c*8);
        bf16x4 lo = {v[0],v[1],v[2],v[3]}, hi = {v[4],v[5],v[6],v[7]};
        *reinterpret_cast<bf16x4*>(&Kl[m*68 + c*8    ]) = lo;
        *reinterpret_cast<bf16x4*>(&Kl[m*68 + c*8 + 4]) = hi;
    }
    for (int id = tid; id < 512; id += 256) {
        const int qq = id >> 6, d = id & 63;
        const int n = qb + qq;
        qs[qq][d] = (n < NTOK_) ? (float)qkv[(size_t)(b*NTOK_+n)*2304 + h*HD_ + d] : 0.0f;
    }
    __syncthreads();
    const int na = qb + wid, nb = qb + wid + 4;
    const bool va = na < NTOK_, vb = nb < NTOK_;
    if (!va) return;
    float sa[4] = {0,0,0,0}, sb[4] = {0,0,0,0};
    for (int d = 0; d < HD_; d += 4) {
        const f32x4 qa = *reinterpret_cast<const f32x4*>(&qs[wid][d]);
        const f32x4 qv = *reinterpret_cast<const f32x4*>(&qs[wid+4][d]);
        #pragma unroll
        for (int j = 0; j < 4; ++j) {
            const int m = lane + 64*j;
            const int mc = m < NTOK_ ? m : NTOK_-1;
            bf16x4 kv = *reinterpret_cast<const bf16x4*>(&Kl[mc*68 + d]);
            float k0=(float)kv[0], k1=(float)kv[1], k2=(float)kv[2], k3=(float)kv[3];
            sa[j] += qa[0]*k0 + qa[1]*k1 + qa[2]*k2 + qa[3]*k3;
            sb[j] += qv[0]*k0 + qv[1]*k1 + qv[2]*k2 + qv[3]*k3;
        }
    }
    #pragma unroll
    for (int j = 0; j < 4; ++j) {
        const bool ok = (lane + 64*j) < NTOK_;
        sa[j] = ok ? sa[j]*0.125f : -3.0e38f;
        sb[j] = ok ? sb[j]*0.125f : -3.0e38f;
    }
    float mxa = fmaxf(fmaxf(sa[0],sa[1]), fmaxf(sa[2],sa[3]));
    float mxb = fmaxf(fmaxf(sb[0],sb[1]), fmaxf(sb[2],sb[3]));
    for (int m=32;m>0;m>>=1) { mxa = fmaxf(mxa, __shfl_xor(mxa,m)); mxb = fmaxf(mxb, __shfl_xor(mxb,m)); }
    float pa[4], pb[4], suma = 0.0f, sumb = 0.0f;
    #pragma unroll
    for (int j = 0; j < 4; ++j) {
        pa[j] = __expf(sa[j]-mxa); suma += pa[j];
        pb[j] = __expf(sb[j]-mxb); sumb += pb[j];
    }
    for (int m=32;m>0;m>>=1) { suma += __shfl_xor(suma,m); sumb += __shfl_xor(sumb,m); }
    #pragma unroll
    for (int j = 0; j < 4; ++j) {
        const int m = lane + 64*j;
        if (m < NTOK_) {
            ps[wid][m] = (bf16_t)pa[j];
            if (vb) ps[wid+4][m] = (bf16_t)pb[j];
        }
    }
    const float inva = 1.0f/suma, invb = 1.0f/sumb;
    const bf16_t* vbase = qkv + (size_t)b*NTOK_*2304 + 1536 + h*HD_ + lane;
    float aa = 0.0f, ab = 0.0f;
    if (vb) {
        for (int m = 0; m < NTOK_; ++m) {
            const float vv = (float)vbase[(size_t)m*2304];
            aa += (float)ps[wid][m]*vv;
            ab += (float)ps[wid+4][m]*vv;
        }
    } else {
        for (int m = 0; m < NTOK_; ++m)
            aa += (float)ps[wid][m]*(float)vbase[(size_t)m*2304];
    }
    out[(size_t)(b*NTOK_+na)*D_ + h*HD_ + lane] = (bf16_t)(aa*inva);
    if (vb) out[(size_t)(b*NTOK_+nb)*D_ + h*HD_ + lane] = (bf16_t)(ab*invb);
}

// ---------------- head: wave per class ---------------------------------------
__global__ __launch_bounds__(256) void k_head(const float* __restrict__ zn,
        const float* __restrict__ hw, const float* __restrict__ hb,
        float* __restrict__ out)
{
    const int o = blockIdx.x*4 + (threadIdx.x >> 6);
    const int b = blockIdx.y;
    const int lane = threadIdx.x & 63;
    if (o >= NCLS_) return;
    float acc = 0.0f;
    #pragma unroll 4
    for (int k = lane; k < D_; k += 64)
        acc = fmaf(zn[b*D_+k], hw[(size_t)o*D_+k], acc);
    for (int m=32;m>0;m>>=1) acc += __shfl_xor(acc, m);
    if (lane == 0) out[b*NCLS_+o] = acc + hb[o];
}

// =============================================================================
extern "C" void kernel_launch(void* const* d_in, const int* in_sizes, int n_in,
                              void* d_out, int out_size, void* d_ws, size_t ws_size,
                              hipStream_t stream)
{
    const float* x        = (const float*)d_in[0];
    const float* patch_w  = (const float*)d_in[1];
    const float* patch_b  = (const float*)d_in[2];
    const float* cls_tok  = (const float*)d_in[3];
    const float* pos_emb  = (const float*)d_in[4];
    const float* ln1_w    = (const float*)d_in[5];
    const float* ln1_b    = (const float*)d_in[6];
    const float* qkv_w    = (const float*)d_in[7];
    const float* qkv_b    = (const float*)d_in[8];
    const float* proj_w   = (const float*)d_in[9];
    const float* proj_b   = (const float*)d_in[10];
    const float* ln2_w    = (const float*)d_in[11];
    const float* ln2_b    = (const float*)d_in[12];
    const float* fc1_w    = (const float*)d_in[13];
    const float* fc1_b    = (const float*)d_in[14];
    const float* fc2_w    = (const float*)d_in[15];
    const float* fc2_b    = (const float*)d_in[16];
    const float* gate_w   = (const float*)d_in[17];
    const float* gate_b   = (const float*)d_in[18];
    const float* exp_w1   = (const float*)d_in[19];
    const float* exp_b1   = (const float*)d_in[20];
    const float* exp_w2   = (const float*)d_in[21];
    const float* exp_b2   = (const float*)d_in[22];
    const float* norm_w   = (const float*)d_in[23];
    const float* norm_b   = (const float*)d_in[24];
    const float* head_w   = (const float*)d_in[25];
    const float* head_b   = (const float*)d_in[26];

    char* wsb = (char*)d_ws;
    size_t off_ = 0;
    auto alloc = [&](size_t nelem, size_t esz) -> void* {
        void* p = wsb + off_;
        off_ += ((nelem*esz + 255) / 256) * 256;
        return p;
    };
    float*  z      = (float*) alloc((size_t)T_*D_, 4);
    bf16_t* lnbuf  = (bf16_t*)alloc((size_t)T_*D_, 2);
    bf16_t* qkvbuf = (bf16_t*)alloc((size_t)T_*3*D_, 2);
    bf16_t* abuf   = (bf16_t*)alloc((size_t)T_*D_, 2);
    bf16_t* hid    = (bf16_t*)alloc((size_t)NSLOT_*DH_, 2);
    float*  pp     = (float*) alloc((size_t)2*T_*D_, 4);      // split-K partials (proj/fc2)
    float*  mp     = (float*) alloc((size_t)2*NSLOT_*D_, 4);  // split-K partials (moe2)
    float*  t_sc   = (float*) alloc(NSLOT_, 4);
    float*  zn     = (float*) alloc((size_t)B_*D_, 4);
    int*    t_e    = (int*)   alloc(NSLOT_, 4);
    int*    rg     = (int*)   alloc(NSLOT_, 4);
    int*    gidx   = (int*)   alloc(NSLOT_, 4);
    int*    offs   = (int*)   alloc(8, 4);
    int*    counts = (int*)   alloc(8, 4);
    const size_t n_patch = (size_t)D_*D_;
    const size_t n_qkv   = (size_t)DEPTH_*3*D_*D_;
    const size_t n_proj  = (size_t)DEPTH_*D_*D_;
    const size_t n_fc1   = (size_t)6*DH_*D_;
    const size_t n_fc2   = (size_t)6*D_*DH_;
    const size_t n_e1    = (size_t)6*NE_*DH_*D_;
    const size_t n_e2    = (size_t)6*NE_*D_*DH_;
    bf16_t* wb_patch = (bf16_t*)alloc(n_patch, 2);
    bf16_t* wb_qkv   = (bf16_t*)alloc(n_qkv, 2);
    bf16_t* wb_proj  = (bf16_t*)alloc(n_proj, 2);
    bf16_t* wb_fc1   = (bf16_t*)alloc(n_fc1, 2);
    bf16_t* wb_fc2   = (bf16_t*)alloc(n_fc2, 2);
    bf16_t* wb_e1    = (bf16_t*)alloc(n_e1, 2);
    bf16_t* wb_e2    = (bf16_t*)alloc(n_e2, 2);
    bf16_t* pbuf   = hid;      // patch staging, dead before fc1 first writes hid
    float*  pout   = mp;       // patch-proj f32 out, dead before moe2 writes mp

    // ---- weight pre-convert (f32 -> bf16) ----
    auto cvt = [&](const float* src, bf16_t* dst, size_t n){
        k_cvt<<<dim3((unsigned)((n/8 + 255)/256)), 256, 0, stream>>>(src, dst, (int)n);
    };
    cvt(patch_w, wb_patch, n_patch);
    cvt(qkv_w,   wb_qkv,   n_qkv);
    cvt(proj_w,  wb_proj,  n_proj);
    cvt(fc1_w,   wb_fc1,   n_fc1);
    cvt(fc2_w,   wb_fc2,   n_fc2);
    cvt(exp_w1,  wb_e1,    n_e1);
    cvt(exp_w2,  wb_e2,    n_e2);

    // ---- patch embedding + assemble + LN1(layer 0) ----
    k_patch_gather<<<dim3((TP_*D_+255)/256), 256, 0, stream>>>(x, pbuf);
    k_dgemm<0,0,0,0,1,0><<<dim3(D_/128, (TP_+63)/64), 256, 0, stream>>>(
        pbuf, nullptr, wb_patch, patch_b, pout, TP_, D_, D_, nullptr, nullptr);
    k_asmln<<<T_, 256, 0, stream>>>(pout, cls_tok, pos_emb, z, ln1_w, ln1_b, lnbuf);

    const int GY = (T_+63)/64;   // 25
    int di = 0, mi = 0;
    for (int i = 0; i < DEPTH_; ++i){
        // lnbuf holds LN1(z) on entry
        k_dgemm<0,0,0,1,1,0><<<dim3(3*D_/128, GY), 256, 0, stream>>>(
            lnbuf, nullptr, wb_qkv + (size_t)i*3*D_*D_, qkv_b + (size_t)i*3*D_,
            qkvbuf, T_, 3*D_, D_, nullptr, nullptr);
        k_attn<<<dim3((NTOK_+7)/8, NH_, B_), 256, 0, stream>>>(qkvbuf, abuf);
        k_dgemm<0,0,0,0,1,1><<<dim3(D_/128, GY), 256, 0, stream>>>(
            abuf, nullptr, wb_proj + (size_t)i*D_*D_, nullptr,
            pp, T_, D_, D_, nullptr, nullptr);
        if (i & 1){ // MoE layers 1,3,5,7,9,11
            k_addln<1,1><<<T_, 256, 0, stream>>>(z, pp, proj_b + i*D_,
                ln2_w + i*D_, ln2_b + i*D_, lnbuf,
                gate_w + (size_t)mi*NE_*D_, gate_b + (size_t)mi*NE_, t_e, t_sc);
            k_scansc<<<1, 1024, 0, stream>>>(t_e, gidx, rg, offs, counts);
            k_dgemm<1,1,1,1,1,0><<<dim3(DH_/128, 50, NE_), 256, 0, stream>>>(
                lnbuf, gidx, wb_e1 + (size_t)mi*NE_*DH_*D_, exp_b1 + (size_t)mi*NE_*DH_,
                hid, NSLOT_, DH_, D_, offs, counts);
            k_dgemm<0,0,1,0,2,1><<<dim3(D_/128, 100, NE_), 256, 0, stream>>>(
                hid, nullptr, wb_e2 + (size_t)mi*NE_*D_*DH_, nullptr,
                mp, NSLOT_, D_, DH_, offs, counts);
            if (i + 1 < DEPTH_) {
                k_comb<1><<<T_, 256, 0, stream>>>(mp, exp_b2 + (size_t)mi*NE_*D_,
                    t_e, rg, t_sc, z, ln1_w + (i+1)*D_, ln1_b + (i+1)*D_, lnbuf);
            } else {
                k_comb<0><<<T_, 256, 0, stream>>>(mp, exp_b2 + (size_t)mi*NE_*D_,
                    t_e, rg, t_sc, z, nullptr, nullptr, nullptr);
            }
            mi++;
        } else {
            k_addln<0,1><<<T_, 256, 0, stream>>>(z, pp, proj_b + i*D_,
                ln2_w + i*D_, ln2_b + i*D_, lnbuf,
                nullptr, nullptr, nullptr, nullptr);
            k_dgemm<1,0,0,1,1,0><<<dim3(DH_/128, GY), 256, 0, stream>>>(
                lnbuf, nullptr, wb_fc1 + (size_t)di*DH_*D_, fc1_b + (size_t)di*DH_,
                hid, T_, DH_, D_, nullptr, nullptr);
            k_dgemm<0,0,0,0,2,1><<<dim3(D_/128, GY, 2), 256, 0, stream>>>(
                hid, nullptr, wb_fc2 + (size_t)di*D_*DH_, nullptr,
                pp, T_, D_, DH_, nullptr, nullptr);
            k_addln<0,2><<<T_, 256, 0, stream>>>(z, pp, fc2_b + di*D_,
                ln1_w + (i+1)*D_, ln1_b + (i+1)*D_, lnbuf,
                nullptr, nullptr, nullptr, nullptr);
            di++;
        }
    }
    // ---- final LN on cls tokens only + head ----
    k_ln<float><<<B_, 256, 0, stream>>>(z, norm_w, norm_b, zn, NTOK_);
    k_head<<<dim3((NCLS_+3)/4, B_), 256, 0, stream>>>(zn, head_w, head_b, (float*)d_out);
}

// Round 18
// 2544.295 us; speedup vs baseline: 1.0004x; 1.0004x over previous
//
#include <hip/hip_runtime.h>
#include <hip/hip_bf16.h>
#include <math.h>

#define B_     8
#define IMG_   224
#define PATCH_ 16
#define CIN_   3
#define D_     768
#define NH_    12
#define DEPTH_ 12
#define NE_    8
#define NCLS_  1000
#define DH_    3072
#define HD_    64
#define GRD_   14
#define NPAT_  196
#define NTOK_  197
#define T_     (B_*NTOK_)    /* 1576 tokens */
#define TP_    (B_*NPAT_)    /* 1568 patches */
#define NSLOT_ (T_*2)        /* 3152 (token,slot) pairs */

typedef __bf16 bf16_t;
typedef __bf16 bf16x8 __attribute__((ext_vector_type(8)));
typedef __bf16 bf16x4 __attribute__((ext_vector_type(4)));
typedef float  f32x4  __attribute__((ext_vector_type(4)));

static __device__ __forceinline__ float gelu_f(float x){
    return 0.5f * x * (1.0f + erff(x * 0.70710678118654752440f));
}

// ---------------- f32 -> bf16 bulk convert (16 elems/thread) -----------------
// Two independent float4-pairs per thread (2x MLP vs the 8-elem version that
// measured ~3.4 TB/s in r12). All weight tensors are multiples of 16 elems.
__global__ __launch_bounds__(256) void k_cvt(const float* __restrict__ in,
                                             bf16_t* __restrict__ out, long n){
    long i = ((long)blockIdx.x*256 + threadIdx.x)*16;
    if (i >= n) return;
    float4 a0 = *reinterpret_cast<const float4*>(in + i);
    float4 a1 = *reinterpret_cast<const float4*>(in + i + 4);
    float4 b0 = *reinterpret_cast<const float4*>(in + i + 8);
    float4 b1 = *reinterpret_cast<const float4*>(in + i + 12);
    bf16x8 h0, h1;
    h0[0]=(bf16_t)a0.x; h0[1]=(bf16_t)a0.y; h0[2]=(bf16_t)a0.z; h0[3]=(bf16_t)a0.w;
    h0[4]=(bf16_t)a1.x; h0[5]=(bf16_t)a1.y; h0[6]=(bf16_t)a1.z; h0[7]=(bf16_t)a1.w;
    h1[0]=(bf16_t)b0.x; h1[1]=(bf16_t)b0.y; h1[2]=(bf16_t)b0.z; h1[3]=(bf16_t)b0.w;
    h1[4]=(bf16_t)b1.x; h1[5]=(bf16_t)b1.y; h1[6]=(bf16_t)b1.z; h1[7]=(bf16_t)b1.w;
    *reinterpret_cast<bf16x8*>(out + i)     = h0;
    *reinterpret_cast<bf16x8*>(out + i + 8) = h1;
}

// ---------------- patch gather: x[B,3,224,224] -> pbuf[1568,768] bf16 -------
__global__ void k_patch_gather(const float* __restrict__ x, bf16_t* __restrict__ pbuf){
    int idx = blockIdx.x*256 + threadIdx.x;
    if (idx >= TP_*D_) return;
    int k  = idx % D_;
    int tp = idx / D_;
    int p  = tp % NPAT_, b = tp / NPAT_;
    int c  = k >> 8;
    int ij = k & 255;
    int i  = ij >> 4, j = ij & 15;
    int gi = p / GRD_, gj = p % GRD_;
    pbuf[idx] = (bf16_t)x[(((size_t)b*CIN_ + c)*IMG_ + gi*PATCH_ + i)*IMG_ + gj*PATCH_ + j];
}

// ---------------- unified bf16 MFMA GEMM: BK=128 single buffer ---------------
// BM=64, BN=128, BK=128, 256 threads (4 waves x 32x64 output), 48KB LDS
// (single buffer) -> 3 blk/CU. r16-validated on dense (grid-limited: halves
// the serial K-chain's drain count); r17 confirmed MoE-neutral (occupancy-
// hidden). Swizzle: 16 chunks of 8 bf16 per row; lds chunk lc = global chunk
// lc^(row&7); frag read chunk c at c^(row&7). Row stride 256B -> 2-way bank.
// PARTIAL=1: raw f32 out (no bias/act) [+ ksid*M*N when KSPLIT=2].
template<int ACT, int GATHER, int MOE, int OUTBF, int KSPLIT, int PARTIAL>
__global__ __launch_bounds__(256) void k_dgemm(
    const bf16_t* __restrict__ A, const int* __restrict__ gidx,
    const bf16_t* __restrict__ W, const float* __restrict__ bias,
    void* __restrict__ Cout, int M, int N, int K,
    const int* __restrict__ moff, const int* __restrict__ mcnt)
{
    __shared__ __align__(16) bf16_t As[64*128];
    __shared__ __align__(16) bf16_t Bs[128*128];
    const int tid = threadIdx.x, lane = tid & 63, w = tid >> 6;
    int row_begin, Mhi, ksid;
    if (MOE) {
        const int e = blockIdx.z;
        const int o = moff[e], c = mcnt[e];
        const int rb = (KSPLIT == 2) ? (int)(blockIdx.y >> 1) : (int)blockIdx.y;
        ksid = (KSPLIT == 2) ? (int)(blockIdx.y & 1) : 0;
        row_begin = o + rb*64;
        Mhi = o + c;
        if (row_begin >= Mhi) return;
        W += (size_t)e*N*K;
        if (!PARTIAL) bias += (size_t)e*N;
    } else {
        row_begin = blockIdx.y*64;
        ksid = (KSPLIT == 2) ? (int)blockIdx.z : 0;
        Mhi = M;
    }
    const int bn = blockIdx.x*128;
    const int KL = K / KSPLIT;

    // staging: 4 rows per wave-load (lane>>4 row-in-segment, lane&15 chunk)
    // A: 16 segments of 4 rows -> 4 per wave; B: 32 segments -> 8 per wave
    const bf16_t* aG[4];
    int aOff[4];
    #pragma unroll
    for (int i = 0; i < 4; ++i) {
        const int s = w*4 + i;
        const int row_l = s*4 + (lane >> 4);
        const int cc = (lane & 15) ^ (row_l & 7);
        const int gg = min(row_begin + row_l, Mhi - 1);
        const int tok = GATHER ? (gidx[gg] >> 1) : gg;
        aG[i] = A + (size_t)tok*K + ksid*KL + cc*8;
        aOff[i] = s*512;
    }
    const bf16_t* wG[8];
    int wOff[8];
    #pragma unroll
    for (int j = 0; j < 8; ++j) {
        const int s = w*8 + j;
        const int row_l = s*4 + (lane >> 4);
        const int cc = (lane & 15) ^ (row_l & 7);
        wG[j] = W + (size_t)(bn + row_l)*K + ksid*KL + cc*8;
        wOff[j] = s*512;
    }
    // frag read byte offsets: row stride 256B; chunk c = ks*4+kg, ks in [0,4)
    const int wm = (w >> 1)*32, wn = (w & 1)*64;
    const int fr = lane & 15, kg = lane >> 4;
    int offA[4][2], offB[4][4];
    #pragma unroll
    for (int ks = 0; ks < 4; ++ks) {
        #pragma unroll
        for (int t = 0; t < 2; ++t) {
            const int ra = wm + t*16 + fr;
            offA[ks][t] = ra*256 + (((ks*4 + kg) ^ (ra & 7)) << 4);
        }
        #pragma unroll
        for (int t = 0; t < 4; ++t) {
            const int rb2 = wn + t*16 + fr;
            offB[ks][t] = rb2*256 + (((ks*4 + kg) ^ (rb2 & 7)) << 4);
        }
    }

    f32x4 acc[2][4] = {};
    const int nt = KL >> 7;
    for (int t = 0; t < nt; ++t) {
        if (t) __syncthreads();            // prior reads of As/Bs complete
        #pragma unroll
        for (int i = 0; i < 4; ++i) {
            __builtin_amdgcn_global_load_lds(
                (const __attribute__((address_space(1))) void*)(aG[i]),
                (__attribute__((address_space(3))) void*)(&As[aOff[i]]), 16, 0, 0);
            aG[i] += 128;
        }
        #pragma unroll
        for (int j = 0; j < 8; ++j) {
            __builtin_amdgcn_global_load_lds(
                (const __attribute__((address_space(1))) void*)(wG[j]),
                (__attribute__((address_space(3))) void*)(&Bs[wOff[j]]), 16, 0, 0);
            wG[j] += 128;
        }
        __syncthreads();                   // drains vmcnt -> tile ready
        const char* baseA = (const char*)&As[0];
        const char* baseB = (const char*)&Bs[0];
        #pragma unroll
        for (int ks = 0; ks < 4; ++ks) {
            bf16x8 af[2], bf[4];
            #pragma unroll
            for (int t2 = 0; t2 < 2; ++t2)
                af[t2] = *reinterpret_cast<const bf16x8*>(baseA + offA[ks][t2]);
            #pragma unroll
            for (int t2 = 0; t2 < 4; ++t2)
                bf[t2] = *reinterpret_cast<const bf16x8*>(baseB + offB[ks][t2]);
            #pragma unroll
            for (int mt = 0; mt < 2; ++mt)
                #pragma unroll
                for (int nt2 = 0; nt2 < 4; ++nt2)
                    acc[mt][nt2] = __builtin_amdgcn_mfma_f32_16x16x32_bf16(
                        af[mt], bf[nt2], acc[mt][nt2], 0, 0, 0);
        }
    }
    float*  Cf = (float*)Cout + ((PARTIAL && KSPLIT == 2) ? (size_t)ksid*M*N : (size_t)0);
    bf16_t* Cb = (bf16_t*)Cout;
    const int cr = kg*4;
    #pragma unroll
    for (int nt2 = 0; nt2 < 4; ++nt2) {
        const int n = bn + wn + nt2*16 + fr;
        const float bv = PARTIAL ? 0.0f : bias[n];
        #pragma unroll
        for (int mt = 0; mt < 2; ++mt) {
            #pragma unroll
            for (int r2 = 0; r2 < 4; ++r2) {
                const int m = row_begin + wm + mt*16 + cr + r2;
                if (m < Mhi) {
                    float v = acc[mt][nt2][r2] + bv;
                    if (ACT) v = gelu_f(v);
                    if (OUTBF) Cb[(size_t)m*N + n] = (bf16_t)v;
                    else       Cf[(size_t)m*N + n] = v;
                }
            }
        }
    }
}

// ---------------- LN core (device) -------------------------------------------
struct LNOut { float y0, y1, y2; };
static __device__ __forceinline__ LNOut ln_block(float v0, float v1, float v2,
        const float* __restrict__ w, const float* __restrict__ b,
        float* red, int tid)
{
    const int wid = tid >> 6, lane = tid & 63;
    float s = v0 + v1 + v2;
    for (int m=32;m>0;m>>=1) s += __shfl_xor(s, m);
    if (lane == 0) red[wid] = s;
    __syncthreads();
    if (tid == 0) red[4] = (red[0]+red[1]+red[2]+red[3]) * (1.0f/768.0f);
    __syncthreads();
    const float mean = red[4];
    float d0 = v0-mean, d1 = v1-mean, d2 = v2-mean;
    float q = d0*d0 + d1*d1 + d2*d2;
    for (int m=32;m>0;m>>=1) q += __shfl_xor(q, m);
    if (lane == 0) red[wid] = q;
    __syncthreads();
    if (tid == 0) {
        float var = (red[0]+red[1]+red[2]+red[3]) * (1.0f/768.0f);
        red[5] = 1.0f / sqrtf(var + 1e-5f);
    }
    __syncthreads();
    const float rstd = red[5];
    LNOut o;
    o.y0 = d0*rstd*w[tid    ] + b[tid    ];
    o.y1 = d1*rstd*w[tid+256] + b[tid+256];
    o.y2 = d2*rstd*w[tid+512] + b[tid+512];
    return o;
}

// ---------------- plain LayerNorm (final) ------------------------------------
template<typename TOUT>
__global__ __launch_bounds__(256) void k_ln(const float* __restrict__ X,
        const float* __restrict__ w, const float* __restrict__ b,
        TOUT* __restrict__ Y, int in_mul)
{
    __shared__ float red[8];
    const int r = blockIdx.x, tid = threadIdx.x;
    const float* xr = X + (size_t)r*in_mul*D_;
    LNOut o = ln_block(xr[tid], xr[tid+256], xr[tid+512], w, b, red, tid);
    TOUT* yr = Y + (size_t)r*D_;
    yr[tid] = (TOUT)o.y0; yr[tid+256] = (TOUT)o.y1; yr[tid+512] = (TOUT)o.y2;
}

// ---------------- assemble (cls/patch + pos) + LN1 of layer 0 ----------------
__global__ __launch_bounds__(256) void k_asmln(const float* __restrict__ pe,
        const float* __restrict__ cls, const float* __restrict__ pos,
        float* __restrict__ z, const float* __restrict__ w,
        const float* __restrict__ b, bf16_t* __restrict__ Y)
{
    __shared__ float red[8];
    const int t = blockIdx.x, tid = threadIdx.x;
    const int bb = t / NTOK_, r = t % NTOK_;
    float v[3];
    #pragma unroll
    for (int j = 0; j < 3; ++j) {
        const int n = tid + j*256;
        if (r == 0) v[j] = cls[n] + pos[n];
        else        v[j] = pe[((size_t)bb*NPAT_ + (r-1))*D_ + n] + pos[(size_t)r*D_ + n];
        z[(size_t)t*D_ + n] = v[j];
    }
    LNOut o = ln_block(v[0], v[1], v[2], w, b, red, tid);
    bf16_t* yr = Y + (size_t)t*D_;
    yr[tid] = (bf16_t)o.y0; yr[tid+256] = (bf16_t)o.y1; yr[tid+512] = (bf16_t)o.y2;
}

// -------- z += P0(+P1)+bias; LN -> Y; optional MoE gate ----------------------
template<int GATE, int NP>
__global__ __launch_bounds__(256) void k_addln(
    float* __restrict__ z, const float* __restrict__ P,
    const float* __restrict__ bias,
    const float* __restrict__ w, const float* __restrict__ b,
    bf16_t* __restrict__ Y,
    const float* __restrict__ gw, const float* __restrict__ gb,
    int* __restrict__ t_e, float* __restrict__ t_sc)
{
    __shared__ float red[8];
    __shared__ float red2[4][8];
    const int t = blockIdx.x, tid = threadIdx.x;
    const int wid = tid >> 6, lane = tid & 63;
    const float* P1 = P + (size_t)T_*D_;
    float v[3];
    #pragma unroll
    for (int j = 0; j < 3; ++j) {
        const int n = tid + j*256;
        float nv = z[(size_t)t*D_+n] + P[(size_t)t*D_+n] + bias[n];
        if (NP == 2) nv += P1[(size_t)t*D_+n];
        z[(size_t)t*D_+n] = nv;
        v[j] = nv;
    }
    LNOut o = ln_block(v[0], v[1], v[2], w, b, red, tid);
    bf16_t* yr = Y + (size_t)t*D_;
    yr[tid] = (bf16_t)o.y0; yr[tid+256] = (bf16_t)o.y1; yr[tid+512] = (bf16_t)o.y2;
    if (GATE) {
        float p[NE_];
        #pragma unroll
        for (int e = 0; e < NE_; ++e)
            p[e] = o.y0*gw[e*D_+tid] + o.y1*gw[e*D_+tid+256] + o.y2*gw[e*D_+tid+512];
        #pragma unroll
        for (int e = 0; e < NE_; ++e)
            for (int m=32;m>0;m>>=1) p[e] += __shfl_xor(p[e], m);
        if (lane == 0)
            #pragma unroll
            for (int e = 0; e < NE_; ++e) red2[wid][e] = p[e];
        __syncthreads();
        if (tid == 0) {
            float l[NE_];
            #pragma unroll
            for (int e = 0; e < NE_; ++e)
                l[e] = red2[0][e]+red2[1][e]+red2[2][e]+red2[3][e] + gb[e];
            int i0 = 0;
            for (int e = 1; e < NE_; ++e) if (l[e] > l[i0]) i0 = e;
            int i1 = -1;
            for (int e = 0; e < NE_; ++e) if (e != i0 && (i1 < 0 || l[e] > l[i1])) i1 = e;
            float e1 = __expf(l[i1] - l[i0]);
            float s = 1.0f + e1;
            t_e[t*2]   = i0;   t_e[t*2+1]  = i1;
            t_sc[t*2]  = 1.0f/s; t_sc[t*2+1] = e1/s;
        }
    }
}

// ---------------- scan+scatter: one block ------------------------------------
__global__ __launch_bounds__(1024) void k_scansc(const int* __restrict__ t_e,
        int* __restrict__ gidx, int* __restrict__ rg,
        int* __restrict__ offs, int* __restrict__ counts)
{
    __shared__ int h[NE_], o[NE_], c2[NE_];
    const int tid = threadIdx.x;
    if (tid < NE_) h[tid] = 0;
    __syncthreads();
    for (int id = tid; id < NSLOT_; id += 1024) atomicAdd(&h[t_e[id]], 1);
    __syncthreads();
    if (tid == 0) {
        int s = 0;
        for (int e = 0; e < NE_; ++e) { o[e] = s; s += h[e]; c2[e] = 0; }
    }
    __syncthreads();
    if (tid < NE_) { offs[tid] = o[tid]; counts[tid] = h[tid]; }
    for (int id = tid; id < NSLOT_; id += 1024) {
        int e = t_e[id];
        int pos = atomicAdd(&c2[e], 1);
        int g = o[e] + pos;
        gidx[g] = id;
        rg[id] = g;
    }
}

// -------- MoE combine from 2 partials (+expert bias); optional next-LN -------
template<int LN>
__global__ __launch_bounds__(256) void k_comb(
    const float* __restrict__ mp, const float* __restrict__ b2,
    const int* __restrict__ t_e, const int* __restrict__ rg,
    const float* __restrict__ t_sc, float* __restrict__ z,
    const float* __restrict__ w, const float* __restrict__ b,
    bf16_t* __restrict__ Y)
{
    __shared__ float red[8];
    const int t = blockIdx.x, tid = threadIdx.x;
    const int g0 = rg[2*t], g1 = rg[2*t+1];
    const int e0 = t_e[2*t], e1 = t_e[2*t+1];
    const float s0 = t_sc[2*t], s1 = t_sc[2*t+1];
    const float* mp1 = mp + (size_t)NSLOT_*D_;
    float v[3];
    #pragma unroll
    for (int j = 0; j < 3; ++j) {
        const int n = tid + j*256;
        float y0 = mp[(size_t)g0*D_+n] + mp1[(size_t)g0*D_+n] + b2[(size_t)e0*D_+n];
        float y1 = mp[(size_t)g1*D_+n] + mp1[(size_t)g1*D_+n] + b2[(size_t)e1*D_+n];
        float nv = z[(size_t)t*D_+n] + s0*y0 + s1*y1;
        z[(size_t)t*D_+n] = nv;
        v[j] = nv;
    }
    if (LN) {
        LNOut o = ln_block(v[0], v[1], v[2], w, b, red, tid);
        bf16_t* yr = Y + (size_t)t*D_;
        yr[tid] = (bf16_t)o.y0; yr[tid+256] = (bf16_t)o.y1; yr[tid+512] = (bf16_t)o.y2;
    }
}

// ---------------- attention: wave-per-2-queries, barrier-free ----------------
__global__ __launch_bounds__(256) void k_attn(const bf16_t* __restrict__ qkv,
                                              bf16_t* __restrict__ out)
{
    __shared__ bf16_t Kl[NTOK_*68];
    __shared__ float  qs[8][64];
    __shared__ bf16_t ps[8][200];
    const int qb = blockIdx.x*8;
    const int h = blockIdx.y, b = blockIdx.z;
    const int tid = threadIdx.x, lane = tid & 63, wid = tid >> 6;
    for (int id = tid; id < NTOK_*8; id += 256) {
        const int m = id >> 3, c = id & 7;
        bf16x8 v = *reinterpret_cast<const bf16x8*>(
            qkv + (size_t)(b*NTOK_+m)*2304 + 768 + h*HD_ + c*8);
        bf16x4 lo = {v[0],v[1],v[2],v[3]}, hi = {v[4],v[5],v[6],v[7]};
        *reinterpret_cast<bf16x4*>(&Kl[m*68 + c*8    ]) = lo;
        *reinterpret_cast<bf16x4*>(&Kl[m*68 + c*8 + 4]) = hi;
    }
    for (int id = tid; id < 512; id += 256) {
        const int qq = id >> 6, d = id & 63;
        const int n = qb + qq;
        qs[qq][d] = (n < NTOK_) ? (float)qkv[(size_t)(b*NTOK_+n)*2304 + h*HD_ + d] : 0.0f;
    }
    __syncthreads();
    const int na = qb + wid, nb = qb + wid + 4;
    const bool va = na < NTOK_, vb = nb < NTOK_;
    if (!va) return;
    float sa[4] = {0,0,0,0}, sb[4] = {0,0,0,0};
    for (int d = 0; d < HD_; d += 4) {
        const f32x4 qa = *reinterpret_cast<const f32x4*>(&qs[wid][d]);
        const f32x4 qv = *reinterpret_cast<const f32x4*>(&qs[wid+4][d]);
        #pragma unroll
        for (int j = 0; j < 4; ++j) {
            const int m = lane + 64*j;
            const int mc = m < NTOK_ ? m : NTOK_-1;
            bf16x4 kv = *reinterpret_cast<const bf16x4*>(&Kl[mc*68 + d]);
            float k0=(float)kv[0], k1=(float)kv[1], k2=(float)kv[2], k3=(float)kv[3];
            sa[j] += qa[0]*k0 + qa[1]*k1 + qa[2]*k2 + qa[3]*k3;
            sb[j] += qv[0]*k0 + qv[1]*k1 + qv[2]*k2 + qv[3]*k3;
        }
    }
    #pragma unroll
    for (int j = 0; j < 4; ++j) {
        const bool ok = (lane + 64*j) < NTOK_;
        sa[j] = ok ? sa[j]*0.125f : -3.0e38f;
        sb[j] = ok ? sb[j]*0.125f : -3.0e38f;
    }
    float mxa = fmaxf(fmaxf(sa[0],sa[1]), fmaxf(sa[2],sa[3]));
    float mxb = fmaxf(fmaxf(sb[0],sb[1]), fmaxf(sb[2],sb[3]));
    for (int m=32;m>0;m>>=1) { mxa = fmaxf(mxa, __shfl_xor(mxa,m)); mxb = fmaxf(mxb, __shfl_xor(mxb,m)); }
    float pa[4], pb[4], suma = 0.0f, sumb = 0.0f;
    #pragma unroll
    for (int j = 0; j < 4; ++j) {
        pa[j] = __expf(sa[j]-mxa); suma += pa[j];
        pb[j] = __expf(sb[j]-mxb); sumb += pb[j];
    }
    for (int m=32;m>0;m>>=1) { suma += __shfl_xor(suma,m); sumb += __shfl_xor(sumb,m); }
    #pragma unroll
    for (int j = 0; j < 4; ++j) {
        const int m = lane + 64*j;
        if (m < NTOK_) {
            ps[wid][m] = (bf16_t)pa[j];
            if (vb) ps[wid+4][m] = (bf16_t)pb[j];
        }
    }
    const float inva = 1.0f/suma, invb = 1.0f/sumb;
    const bf16_t* vbase = qkv + (size_t)b*NTOK_*2304 + 1536 + h*HD_ + lane;
    float aa = 0.0f, ab = 0.0f;
    if (vb) {
        for (int m = 0; m < NTOK_; ++m) {
            const float vv = (float)vbase[(size_t)m*2304];
            aa += (float)ps[wid][m]*vv;
            ab += (float)ps[wid+4][m]*vv;
        }
    } else {
        for (int m = 0; m < NTOK_; ++m)
            aa += (float)ps[wid][m]*(float)vbase[(size_t)m*2304];
    }
    out[(size_t)(b*NTOK_+na)*D_ + h*HD_ + lane] = (bf16_t)(aa*inva);
    if (vb) out[(size_t)(b*NTOK_+nb)*D_ + h*HD_ + lane] = (bf16_t)(ab*invb);
}

// ---------------- head: wave per class ---------------------------------------
__global__ __launch_bounds__(256) void k_head(const float* __restrict__ zn,
        const float* __restrict__ hw, const float* __restrict__ hb,
        float* __restrict__ out)
{
    const int o = blockIdx.x*4 + (threadIdx.x >> 6);
    const int b = blockIdx.y;
    const int lane = threadIdx.x & 63;
    if (o >= NCLS_) return;
    float acc = 0.0f;
    #pragma unroll 4
    for (int k = lane; k < D_; k += 64)
        acc = fmaf(zn[b*D_+k], hw[(size_t)o*D_+k], acc);
    for (int m=32;m>0;m>>=1) acc += __shfl_xor(acc, m);
    if (lane == 0) out[b*NCLS_+o] = acc + hb[o];
}

// =============================================================================
extern "C" void kernel_launch(void* const* d_in, const int* in_sizes, int n_in,
                              void* d_out, int out_size, void* d_ws, size_t ws_size,
                              hipStream_t stream)
{
    const float* x        = (const float*)d_in[0];
    const float* patch_w  = (const float*)d_in[1];
    const float* patch_b  = (const float*)d_in[2];
    const float* cls_tok  = (const float*)d_in[3];
    const float* pos_emb  = (const float*)d_in[4];
    const float* ln1_w    = (const float*)d_in[5];
    const float* ln1_b    = (const float*)d_in[6];
    const float* qkv_w    = (const float*)d_in[7];
    const float* qkv_b    = (const float*)d_in[8];
    const float* proj_w   = (const float*)d_in[9];
    const float* proj_b   = (const float*)d_in[10];
    const float* ln2_w    = (const float*)d_in[11];
    const float* ln2_b    = (const float*)d_in[12];
    const float* fc1_w    = (const float*)d_in[13];
    const float* fc1_b    = (const float*)d_in[14];
    const float* fc2_w    = (const float*)d_in[15];
    const float* fc2_b    = (const float*)d_in[16];
    const float* gate_w   = (const float*)d_in[17];
    const float* gate_b   = (const float*)d_in[18];
    const float* exp_w1   = (const float*)d_in[19];
    const float* exp_b1   = (const float*)d_in[20];
    const float* exp_w2   = (const float*)d_in[21];
    const float* exp_b2   = (const float*)d_in[22];
    const float* norm_w   = (const float*)d_in[23];
    const float* norm_b   = (const float*)d_in[24];
    const float* head_w   = (const float*)d_in[25];
    const float* head_b   = (const float*)d_in[26];

    char* wsb = (char*)d_ws;
    size_t off_ = 0;
    auto alloc = [&](size_t nelem, size_t esz) -> void* {
        void* p = wsb + off_;
        off_ += ((nelem*esz + 255) / 256) * 256;
        return p;
    };
    float*  z      = (float*) alloc((size_t)T_*D_, 4);
    bf16_t* lnbuf  = (bf16_t*)alloc((size_t)T_*D_, 2);
    bf16_t* qkvbuf = (bf16_t*)alloc((size_t)T_*3*D_, 2);
    bf16_t* abuf   = (bf16_t*)alloc((size_t)T_*D_, 2);
    bf16_t* hid    = (bf16_t*)alloc((size_t)NSLOT_*DH_, 2);
    float*  pp     = (float*) alloc((size_t)2*T_*D_, 4);      // split-K partials (proj/fc2)
    float*  mp     = (float*) alloc((size_t)2*NSLOT_*D_, 4);  // split-K partials (moe2)
    float*  t_sc   = (float*) alloc(NSLOT_, 4);
    float*  zn     = (float*) alloc((size_t)B_*D_, 4);
    int*    t_e    = (int*)   alloc(NSLOT_, 4);
    int*    rg     = (int*)   alloc(NSLOT_, 4);
    int*    gidx   = (int*)   alloc(NSLOT_, 4);
    int*    offs   = (int*)   alloc(8, 4);
    int*    counts = (int*)   alloc(8, 4);
    const size_t n_patch = (size_t)D_*D_;
    const size_t n_qkv   = (size_t)DEPTH_*3*D_*D_;
    const size_t n_proj  = (size_t)DEPTH_*D_*D_;
    const size_t n_fc1   = (size_t)6*DH_*D_;
    const size_t n_fc2   = (size_t)6*D_*DH_;
    const size_t n_e1    = (size_t)6*NE_*DH_*D_;
    const size_t n_e2    = (size_t)6*NE_*D_*DH_;
    bf16_t* wb_patch = (bf16_t*)alloc(n_patch, 2);
    bf16_t* wb_qkv   = (bf16_t*)alloc(n_qkv, 2);
    bf16_t* wb_proj  = (bf16_t*)alloc(n_proj, 2);
    bf16_t* wb_fc1   = (bf16_t*)alloc(n_fc1, 2);
    bf16_t* wb_fc2   = (bf16_t*)alloc(n_fc2, 2);
    bf16_t* wb_e1    = (bf16_t*)alloc(n_e1, 2);
    bf16_t* wb_e2    = (bf16_t*)alloc(n_e2, 2);
    bf16_t* pbuf   = hid;      // patch staging, dead before fc1 first writes hid
    float*  pout   = mp;       // patch-proj f32 out, dead before moe2 writes mp

    // ---- weight pre-convert (f32 -> bf16), 16 elems/thread ----
    auto cvt = [&](const float* src, bf16_t* dst, size_t n){
        k_cvt<<<dim3((unsigned)((n/16 + 255)/256)), 256, 0, stream>>>(src, dst, (long)n);
    };
    cvt(patch_w, wb_patch, n_patch);
    cvt(qkv_w,   wb_qkv,   n_qkv);
    cvt(proj_w,  wb_proj,  n_proj);
    cvt(fc1_w,   wb_fc1,   n_fc1);
    cvt(fc2_w,   wb_fc2,   n_fc2);
    cvt(exp_w1,  wb_e1,    n_e1);
    cvt(exp_w2,  wb_e2,    n_e2);

    // ---- patch embedding + assemble + LN1(layer 0) ----
    k_patch_gather<<<dim3((TP_*D_+255)/256), 256, 0, stream>>>(x, pbuf);
    k_dgemm<0,0,0,0,1,0><<<dim3(D_/128, (TP_+63)/64), 256, 0, stream>>>(
        pbuf, nullptr, wb_patch, patch_b, pout, TP_, D_, D_, nullptr, nullptr);
    k_asmln<<<T_, 256, 0, stream>>>(pout, cls_tok, pos_emb, z, ln1_w, ln1_b, lnbuf);

    const int GY = (T_+63)/64;   // 25
    int di = 0, mi = 0;
    for (int i = 0; i < DEPTH_; ++i){
        // lnbuf holds LN1(z) on entry
        k_dgemm<0,0,0,1,1,0><<<dim3(3*D_/128, GY), 256, 0, stream>>>(
            lnbuf, nullptr, wb_qkv + (size_t)i*3*D_*D_, qkv_b + (size_t)i*3*D_,
            qkvbuf, T_, 3*D_, D_, nullptr, nullptr);
        k_attn<<<dim3((NTOK_+7)/8, NH_, B_), 256, 0, stream>>>(qkvbuf, abuf);
        k_dgemm<0,0,0,0,1,1><<<dim3(D_/128, GY), 256, 0, stream>>>(
            abuf, nullptr, wb_proj + (size_t)i*D_*D_, nullptr,
            pp, T_, D_, D_, nullptr, nullptr);
        if (i & 1){ // MoE layers 1,3,5,7,9,11
            k_addln<1,1><<<T_, 256, 0, stream>>>(z, pp, proj_b + i*D_,
                ln2_w + i*D_, ln2_b + i*D_, lnbuf,
                gate_w + (size_t)mi*NE_*D_, gate_b + (size_t)mi*NE_, t_e, t_sc);
            k_scansc<<<1, 1024, 0, stream>>>(t_e, gidx, rg, offs, counts);
            k_dgemm<1,1,1,1,1,0><<<dim3(DH_/128, 50, NE_), 256, 0, stream>>>(
                lnbuf, gidx, wb_e1 + (size_t)mi*NE_*DH_*D_, exp_b1 + (size_t)mi*NE_*DH_,
                hid, NSLOT_, DH_, D_, offs, counts);
            k_dgemm<0,0,1,0,2,1><<<dim3(D_/128, 100, NE_), 256, 0, stream>>>(
                hid, nullptr, wb_e2 + (size_t)mi*NE_*D_*DH_, nullptr,
                mp, NSLOT_, D_, DH_, offs, counts);
            if (i + 1 < DEPTH_) {
                k_comb<1><<<T_, 256, 0, stream>>>(mp, exp_b2 + (size_t)mi*NE_*D_,
                    t_e, rg, t_sc, z, ln1_w + (i+1)*D_, ln1_b + (i+1)*D_, lnbuf);
            } else {
                k_comb<0><<<T_, 256, 0, stream>>>(mp, exp_b2 + (size_t)mi*NE_*D_,
                    t_e, rg, t_sc, z, nullptr, nullptr, nullptr);
            }
            mi++;
        } else {
            k_addln<0,1><<<T_, 256, 0, stream>>>(z, pp, proj_b + i*D_,
                ln2_w + i*D_, ln2_b + i*D_, lnbuf,
                nullptr, nullptr, nullptr, nullptr);
            k_dgemm<1,0,0,1,1,0><<<dim3(DH_/128, GY), 256, 0, stream>>>(
                lnbuf, nullptr, wb_fc1 + (size_t)di*DH_*D_, fc1_b + (size_t)di*DH_,
                hid, T_, DH_, D_, nullptr, nullptr);
            k_dgemm<0,0,0,0,2,1><<<dim3(D_/128, GY, 2), 256, 0, stream>>>(
                hid, nullptr, wb_fc2 + (size_t)di*D_*DH_, nullptr,
                pp, T_, D_, DH_, nullptr, nullptr);
            k_addln<0,2><<<T_, 256, 0, stream>>>(z, pp, fc2_b + di*D_,
                ln1_w + (i+1)*D_, ln1_b + (i+1)*D_, lnbuf,
                nullptr, nullptr, nullptr, nullptr);
            di++;
        }
    }
    // ---- final LN on cls tokens only + head ----
    k_ln<float><<<B_, 256, 0, stream>>>(z, norm_w, norm_b, zn, NTOK_);
    k_head<<<dim3((NCLS_+3)/4, B_), 256, 0, stream>>>(zn, head_w, head_b, (float*)d_out);
}

// Round 19
// 2519.956 us; speedup vs baseline: 1.0101x; 1.0097x over previous
//
#include <hip/hip_runtime.h>
#include <hip/hip_bf16.h>
#include <math.h>

#define B_     8
#define IMG_   224
#define PATCH_ 16
#define CIN_   3
#define D_     768
#define NH_    12
#define DEPTH_ 12
#define NE_    8
#define NCLS_  1000
#define DH_    3072
#define HD_    64
#define GRD_   14
#define NPAT_  196
#define NTOK_  197
#define T_     (B_*NTOK_)    /* 1576 tokens */
#define TP_    (B_*NPAT_)    /* 1568 patches */
#define NSLOT_ (T_*2)        /* 3152 (token,slot) pairs */

typedef __bf16 bf16_t;
typedef __bf16 bf16x8 __attribute__((ext_vector_type(8)));
typedef __bf16 bf16x4 __attribute__((ext_vector_type(4)));
typedef float  f32x4  __attribute__((ext_vector_type(4)));

static __device__ __forceinline__ float gelu_f(float x){
    return 0.5f * x * (1.0f + erff(x * 0.70710678118654752440f));
}

// ---------------- f32 -> bf16 bulk convert (16 elems/thread) -----------------
__global__ __launch_bounds__(256) void k_cvt(const float* __restrict__ in,
                                             bf16_t* __restrict__ out, long n){
    long i = ((long)blockIdx.x*256 + threadIdx.x)*16;
    if (i >= n) return;
    float4 a0 = *reinterpret_cast<const float4*>(in + i);
    float4 a1 = *reinterpret_cast<const float4*>(in + i + 4);
    float4 b0 = *reinterpret_cast<const float4*>(in + i + 8);
    float4 b1 = *reinterpret_cast<const float4*>(in + i + 12);
    bf16x8 h0, h1;
    h0[0]=(bf16_t)a0.x; h0[1]=(bf16_t)a0.y; h0[2]=(bf16_t)a0.z; h0[3]=(bf16_t)a0.w;
    h0[4]=(bf16_t)a1.x; h0[5]=(bf16_t)a1.y; h0[6]=(bf16_t)a1.z; h0[7]=(bf16_t)a1.w;
    h1[0]=(bf16_t)b0.x; h1[1]=(bf16_t)b0.y; h1[2]=(bf16_t)b0.z; h1[3]=(bf16_t)b0.w;
    h1[4]=(bf16_t)b1.x; h1[5]=(bf16_t)b1.y; h1[6]=(bf16_t)b1.z; h1[7]=(bf16_t)b1.w;
    *reinterpret_cast<bf16x8*>(out + i)     = h0;
    *reinterpret_cast<bf16x8*>(out + i + 8) = h1;
}

// ---------------- patch gather: x[B,3,224,224] -> pbuf[1568,768] bf16 -------
__global__ void k_patch_gather(const float* __restrict__ x, bf16_t* __restrict__ pbuf){
    int idx = blockIdx.x*256 + threadIdx.x;
    if (idx >= TP_*D_) return;
    int k  = idx % D_;
    int tp = idx / D_;
    int p  = tp % NPAT_, b = tp / NPAT_;
    int c  = k >> 8;
    int ij = k & 255;
    int i  = ij >> 4, j = ij & 15;
    int gi = p / GRD_, gj = p % GRD_;
    pbuf[idx] = (bf16_t)x[(((size_t)b*CIN_ + c)*IMG_ + gi*PATCH_ + i)*IMG_ + gj*PATCH_ + j];
}

// ---------------- unified bf16 MFMA GEMM: BK=128 single buffer ---------------
// BM=64, BN=128, BK=128, 256 threads (4 waves x 32x64 output), 48KB LDS
// (single buffer) -> 3 blk/CU. r16-validated on dense (grid-limited: halves
// the serial K-chain's drain count); r17 confirmed MoE-neutral.
// PARTIAL=1: raw f32 out (no bias/act) [+ ksid*M*N when KSPLIT=2].
template<int ACT, int GATHER, int MOE, int OUTBF, int KSPLIT, int PARTIAL>
__global__ __launch_bounds__(256) void k_dgemm(
    const bf16_t* __restrict__ A, const int* __restrict__ gidx,
    const bf16_t* __restrict__ W, const float* __restrict__ bias,
    void* __restrict__ Cout, int M, int N, int K,
    const int* __restrict__ moff, const int* __restrict__ mcnt)
{
    __shared__ __align__(16) bf16_t As[64*128];
    __shared__ __align__(16) bf16_t Bs[128*128];
    const int tid = threadIdx.x, lane = tid & 63, w = tid >> 6;
    int row_begin, Mhi, ksid;
    if (MOE) {
        const int e = blockIdx.z;
        const int o = moff[e], c = mcnt[e];
        const int rb = (KSPLIT == 2) ? (int)(blockIdx.y >> 1) : (int)blockIdx.y;
        ksid = (KSPLIT == 2) ? (int)(blockIdx.y & 1) : 0;
        row_begin = o + rb*64;
        Mhi = o + c;
        if (row_begin >= Mhi) return;
        W += (size_t)e*N*K;
        if (!PARTIAL) bias += (size_t)e*N;
    } else {
        row_begin = blockIdx.y*64;
        ksid = (KSPLIT == 2) ? (int)blockIdx.z : 0;
        Mhi = M;
    }
    const int bn = blockIdx.x*128;
    const int KL = K / KSPLIT;

    const bf16_t* aG[4];
    int aOff[4];
    #pragma unroll
    for (int i = 0; i < 4; ++i) {
        const int s = w*4 + i;
        const int row_l = s*4 + (lane >> 4);
        const int cc = (lane & 15) ^ (row_l & 7);
        const int gg = min(row_begin + row_l, Mhi - 1);
        const int tok = GATHER ? (gidx[gg] >> 1) : gg;
        aG[i] = A + (size_t)tok*K + ksid*KL + cc*8;
        aOff[i] = s*512;
    }
    const bf16_t* wG[8];
    int wOff[8];
    #pragma unroll
    for (int j = 0; j < 8; ++j) {
        const int s = w*8 + j;
        const int row_l = s*4 + (lane >> 4);
        const int cc = (lane & 15) ^ (row_l & 7);
        wG[j] = W + (size_t)(bn + row_l)*K + ksid*KL + cc*8;
        wOff[j] = s*512;
    }
    const int wm = (w >> 1)*32, wn = (w & 1)*64;
    const int fr = lane & 15, kg = lane >> 4;
    int offA[4][2], offB[4][4];
    #pragma unroll
    for (int ks = 0; ks < 4; ++ks) {
        #pragma unroll
        for (int t = 0; t < 2; ++t) {
            const int ra = wm + t*16 + fr;
            offA[ks][t] = ra*256 + (((ks*4 + kg) ^ (ra & 7)) << 4);
        }
        #pragma unroll
        for (int t = 0; t < 4; ++t) {
            const int rb2 = wn + t*16 + fr;
            offB[ks][t] = rb2*256 + (((ks*4 + kg) ^ (rb2 & 7)) << 4);
        }
    }

    f32x4 acc[2][4] = {};
    const int nt = KL >> 7;
    for (int t = 0; t < nt; ++t) {
        if (t) __syncthreads();            // prior reads of As/Bs complete
        #pragma unroll
        for (int i = 0; i < 4; ++i) {
            __builtin_amdgcn_global_load_lds(
                (const __attribute__((address_space(1))) void*)(aG[i]),
                (__attribute__((address_space(3))) void*)(&As[aOff[i]]), 16, 0, 0);
            aG[i] += 128;
        }
        #pragma unroll
        for (int j = 0; j < 8; ++j) {
            __builtin_amdgcn_global_load_lds(
                (const __attribute__((address_space(1))) void*)(wG[j]),
                (__attribute__((address_space(3))) void*)(&Bs[wOff[j]]), 16, 0, 0);
            wG[j] += 128;
        }
        __syncthreads();                   // drains vmcnt -> tile ready
        const char* baseA = (const char*)&As[0];
        const char* baseB = (const char*)&Bs[0];
        #pragma unroll
        for (int ks = 0; ks < 4; ++ks) {
            bf16x8 af[2], bf[4];
            #pragma unroll
            for (int t2 = 0; t2 < 2; ++t2)
                af[t2] = *reinterpret_cast<const bf16x8*>(baseA + offA[ks][t2]);
            #pragma unroll
            for (int t2 = 0; t2 < 4; ++t2)
                bf[t2] = *reinterpret_cast<const bf16x8*>(baseB + offB[ks][t2]);
            #pragma unroll
            for (int mt = 0; mt < 2; ++mt)
                #pragma unroll
                for (int nt2 = 0; nt2 < 4; ++nt2)
                    acc[mt][nt2] = __builtin_amdgcn_mfma_f32_16x16x32_bf16(
                        af[mt], bf[nt2], acc[mt][nt2], 0, 0, 0);
        }
    }
    float*  Cf = (float*)Cout + ((PARTIAL && KSPLIT == 2) ? (size_t)ksid*M*N : (size_t)0);
    bf16_t* Cb = (bf16_t*)Cout;
    const int cr = kg*4;
    #pragma unroll
    for (int nt2 = 0; nt2 < 4; ++nt2) {
        const int n = bn + wn + nt2*16 + fr;
        const float bv = PARTIAL ? 0.0f : bias[n];
        #pragma unroll
        for (int mt = 0; mt < 2; ++mt) {
            #pragma unroll
            for (int r2 = 0; r2 < 4; ++r2) {
                const int m = row_begin + wm + mt*16 + cr + r2;
                if (m < Mhi) {
                    float v = acc[mt][nt2][r2] + bv;
                    if (ACT) v = gelu_f(v);
                    if (OUTBF) Cb[(size_t)m*N + n] = (bf16_t)v;
                    else       Cf[(size_t)m*N + n] = v;
                }
            }
        }
    }
}

// ---------------- LN core (device) -------------------------------------------
struct LNOut { float y0, y1, y2; };
static __device__ __forceinline__ LNOut ln_block(float v0, float v1, float v2,
        const float* __restrict__ w, const float* __restrict__ b,
        float* red, int tid)
{
    const int wid = tid >> 6, lane = tid & 63;
    float s = v0 + v1 + v2;
    for (int m=32;m>0;m>>=1) s += __shfl_xor(s, m);
    if (lane == 0) red[wid] = s;
    __syncthreads();
    if (tid == 0) red[4] = (red[0]+red[1]+red[2]+red[3]) * (1.0f/768.0f);
    __syncthreads();
    const float mean = red[4];
    float d0 = v0-mean, d1 = v1-mean, d2 = v2-mean;
    float q = d0*d0 + d1*d1 + d2*d2;
    for (int m=32;m>0;m>>=1) q += __shfl_xor(q, m);
    if (lane == 0) red[wid] = q;
    __syncthreads();
    if (tid == 0) {
        float var = (red[0]+red[1]+red[2]+red[3]) * (1.0f/768.0f);
        red[5] = 1.0f / sqrtf(var + 1e-5f);
    }
    __syncthreads();
    const float rstd = red[5];
    LNOut o;
    o.y0 = d0*rstd*w[tid    ] + b[tid    ];
    o.y1 = d1*rstd*w[tid+256] + b[tid+256];
    o.y2 = d2*rstd*w[tid+512] + b[tid+512];
    return o;
}

// ---------------- plain LayerNorm (final) ------------------------------------
template<typename TOUT>
__global__ __launch_bounds__(256) void k_ln(const float* __restrict__ X,
        const float* __restrict__ w, const float* __restrict__ b,
        TOUT* __restrict__ Y, int in_mul)
{
    __shared__ float red[8];
    const int r = blockIdx.x, tid = threadIdx.x;
    const float* xr = X + (size_t)r*in_mul*D_;
    LNOut o = ln_block(xr[tid], xr[tid+256], xr[tid+512], w, b, red, tid);
    TOUT* yr = Y + (size_t)r*D_;
    yr[tid] = (TOUT)o.y0; yr[tid+256] = (TOUT)o.y1; yr[tid+512] = (TOUT)o.y2;
}

// ---------------- assemble (cls/patch + pos) + LN1 of layer 0 ----------------
__global__ __launch_bounds__(256) void k_asmln(const float* __restrict__ pe,
        const float* __restrict__ cls, const float* __restrict__ pos,
        float* __restrict__ z, const float* __restrict__ w,
        const float* __restrict__ b, bf16_t* __restrict__ Y)
{
    __shared__ float red[8];
    const int t = blockIdx.x, tid = threadIdx.x;
    const int bb = t / NTOK_, r = t % NTOK_;
    float v[3];
    #pragma unroll
    for (int j = 0; j < 3; ++j) {
        const int n = tid + j*256;
        if (r == 0) v[j] = cls[n] + pos[n];
        else        v[j] = pe[((size_t)bb*NPAT_ + (r-1))*D_ + n] + pos[(size_t)r*D_ + n];
        z[(size_t)t*D_ + n] = v[j];
    }
    LNOut o = ln_block(v[0], v[1], v[2], w, b, red, tid);
    bf16_t* yr = Y + (size_t)t*D_;
    yr[tid] = (bf16_t)o.y0; yr[tid+256] = (bf16_t)o.y1; yr[tid+512] = (bf16_t)o.y2;
}

// -------- z += P0(+P1)+bias; LN -> Y; optional MoE gate ----------------------
template<int GATE, int NP>
__global__ __launch_bounds__(256) void k_addln(
    float* __restrict__ z, const float* __restrict__ P,
    const float* __restrict__ bias,
    const float* __restrict__ w, const float* __restrict__ b,
    bf16_t* __restrict__ Y,
    const float* __restrict__ gw, const float* __restrict__ gb,
    int* __restrict__ t_e, float* __restrict__ t_sc)
{
    __shared__ float red[8];
    __shared__ float red2[4][8];
    const int t = blockIdx.x, tid = threadIdx.x;
    const int wid = tid >> 6, lane = tid & 63;
    const float* P1 = P + (size_t)T_*D_;
    float v[3];
    #pragma unroll
    for (int j = 0; j < 3; ++j) {
        const int n = tid + j*256;
        float nv = z[(size_t)t*D_+n] + P[(size_t)t*D_+n] + bias[n];
        if (NP == 2) nv += P1[(size_t)t*D_+n];
        z[(size_t)t*D_+n] = nv;
        v[j] = nv;
    }
    LNOut o = ln_block(v[0], v[1], v[2], w, b, red, tid);
    bf16_t* yr = Y + (size_t)t*D_;
    yr[tid] = (bf16_t)o.y0; yr[tid+256] = (bf16_t)o.y1; yr[tid+512] = (bf16_t)o.y2;
    if (GATE) {
        float p[NE_];
        #pragma unroll
        for (int e = 0; e < NE_; ++e)
            p[e] = o.y0*gw[e*D_+tid] + o.y1*gw[e*D_+tid+256] + o.y2*gw[e*D_+tid+512];
        #pragma unroll
        for (int e = 0; e < NE_; ++e)
            for (int m=32;m>0;m>>=1) p[e] += __shfl_xor(p[e], m);
        if (lane == 0)
            #pragma unroll
            for (int e = 0; e < NE_; ++e) red2[wid][e] = p[e];
        __syncthreads();
        if (tid == 0) {
            float l[NE_];
            #pragma unroll
            for (int e = 0; e < NE_; ++e)
                l[e] = red2[0][e]+red2[1][e]+red2[2][e]+red2[3][e] + gb[e];
            int i0 = 0;
            for (int e = 1; e < NE_; ++e) if (l[e] > l[i0]) i0 = e;
            int i1 = -1;
            for (int e = 0; e < NE_; ++e) if (e != i0 && (i1 < 0 || l[e] > l[i1])) i1 = e;
            float e1 = __expf(l[i1] - l[i0]);
            float s = 1.0f + e1;
            t_e[t*2]   = i0;   t_e[t*2+1]  = i1;
            t_sc[t*2]  = 1.0f/s; t_sc[t*2+1] = e1/s;
        }
    }
}

// ---------------- scan+scatter: one block ------------------------------------
__global__ __launch_bounds__(1024) void k_scansc(const int* __restrict__ t_e,
        int* __restrict__ gidx, int* __restrict__ rg,
        int* __restrict__ offs, int* __restrict__ counts)
{
    __shared__ int h[NE_], o[NE_], c2[NE_];
    const int tid = threadIdx.x;
    if (tid < NE_) h[tid] = 0;
    __syncthreads();
    for (int id = tid; id < NSLOT_; id += 1024) atomicAdd(&h[t_e[id]], 1);
    __syncthreads();
    if (tid == 0) {
        int s = 0;
        for (int e = 0; e < NE_; ++e) { o[e] = s; s += h[e]; c2[e] = 0; }
    }
    __syncthreads();
    if (tid < NE_) { offs[tid] = o[tid]; counts[tid] = h[tid]; }
    for (int id = tid; id < NSLOT_; id += 1024) {
        int e = t_e[id];
        int pos = atomicAdd(&c2[e], 1);
        int g = o[e] + pos;
        gidx[g] = id;
        rg[id] = g;
    }
}

// -------- MoE combine from 2 partials (+expert bias); optional next-LN -------
template<int LN>
__global__ __launch_bounds__(256) void k_comb(
    const float* __restrict__ mp, const float* __restrict__ b2,
    const int* __restrict__ t_e, const int* __restrict__ rg,
    const float* __restrict__ t_sc, float* __restrict__ z,
    const float* __restrict__ w, const float* __restrict__ b,
    bf16_t* __restrict__ Y)
{
    __shared__ float red[8];
    const int t = blockIdx.x, tid = threadIdx.x;
    const int g0 = rg[2*t], g1 = rg[2*t+1];
    const int e0 = t_e[2*t], e1 = t_e[2*t+1];
    const float s0 = t_sc[2*t], s1 = t_sc[2*t+1];
    const float* mp1 = mp + (size_t)NSLOT_*D_;
    float v[3];
    #pragma unroll
    for (int j = 0; j < 3; ++j) {
        const int n = tid + j*256;
        float y0 = mp[(size_t)g0*D_+n] + mp1[(size_t)g0*D_+n] + b2[(size_t)e0*D_+n];
        float y1 = mp[(size_t)g1*D_+n] + mp1[(size_t)g1*D_+n] + b2[(size_t)e1*D_+n];
        float nv = z[(size_t)t*D_+n] + s0*y0 + s1*y1;
        z[(size_t)t*D_+n] = nv;
        v[j] = nv;
    }
    if (LN) {
        LNOut o = ln_block(v[0], v[1], v[2], w, b, red, tid);
        bf16_t* yr = Y + (size_t)t*D_;
        yr[tid] = (bf16_t)o.y0; yr[tid+256] = (bf16_t)o.y1; yr[tid+512] = (bf16_t)o.y2;
    }
}

// ---------------- attention: wave-per-2-queries, barrier-free ----------------
__global__ __launch_bounds__(256) void k_attn(const bf16_t* __restrict__ qkv,
                                              bf16_t* __restrict__ out)
{
    __shared__ bf16_t Kl[NTOK_*68];
    __shared__ float  qs[8][64];
    __shared__ bf16_t ps[8][200];
    const int qb = blockIdx.x*8;
    const int h = blockIdx.y, b = blockIdx.z;
    const int tid = threadIdx.x, lane = tid & 63, wid = tid >> 6;
    for (int id = tid; id < NTOK_*8; id += 256) {
        const int m = id >> 3, c = id & 7;
        bf16x8 v = *reinterpret_cast<const bf16x8*>(
            qkv + (size_t)(b*NTOK_+m)*2304 + 768 + h*HD_ + c*8);
        bf16x4 lo = {v[0],v[1],v[2],v[3]}, hi = {v[4],v[5],v[6],v[7]};
        *reinterpret_cast<bf16x4*>(&Kl[m*68 + c*8    ]) = lo;
        *reinterpret_cast<bf16x4*>(&Kl[m*68 + c*8 + 4]) = hi;
    }
    for (int id = tid; id < 512; id += 256) {
        const int qq = id >> 6, d = id & 63;
        const int n = qb + qq;
        qs[qq][d] = (n < NTOK_) ? (float)qkv[(size_t)(b*NTOK_+n)*2304 + h*HD_ + d] : 0.0f;
    }
    __syncthreads();
    const int na = qb + wid, nb = qb + wid + 4;
    const bool va = na < NTOK_, vb = nb < NTOK_;
    if (!va) return;
    float sa[4] = {0,0,0,0}, sb[4] = {0,0,0,0};
    for (int d = 0; d < HD_; d += 4) {
        const f32x4 qa = *reinterpret_cast<const f32x4*>(&qs[wid][d]);
        const f32x4 qv = *reinterpret_cast<const f32x4*>(&qs[wid+4][d]);
        #pragma unroll
        for (int j = 0; j < 4; ++j) {
            const int m = lane + 64*j;
            const int mc = m < NTOK_ ? m : NTOK_-1;
            bf16x4 kv = *reinterpret_cast<const bf16x4*>(&Kl[mc*68 + d]);
            float k0=(float)kv[0], k1=(float)kv[1], k2=(float)kv[2], k3=(float)kv[3];
            sa[j] += qa[0]*k0 + qa[1]*k1 + qa[2]*k2 + qa[3]*k3;
            sb[j] += qv[0]*k0 + qv[1]*k1 + qv[2]*k2 + qv[3]*k3;
        }
    }
    #pragma unroll
    for (int j = 0; j < 4; ++j) {
        const bool ok = (lane + 64*j) < NTOK_;
        sa[j] = ok ? sa[j]*0.125f : -3.0e38f;
        sb[j] = ok ? sb[j]*0.125f : -3.0e38f;
    }
    float mxa = fmaxf(fmaxf(sa[0],sa[1]), fmaxf(sa[2],sa[3]));
    float mxb = fmaxf(fmaxf(sb[0],sb[1]), fmaxf(sb[2],sb[3]));
    for (int m=32;m>0;m>>=1) { mxa = fmaxf(mxa, __shfl_xor(mxa,m)); mxb = fmaxf(mxb, __shfl_xor(mxb,m)); }
    float pa[4], pb[4], suma = 0.0f, sumb = 0.0f;
    #pragma unroll
    for (int j = 0; j < 4; ++j) {
        pa[j] = __expf(sa[j]-mxa); suma += pa[j];
        pb[j] = __expf(sb[j]-mxb); sumb += pb[j];
    }
    for (int m=32;m>0;m>>=1) { suma += __shfl_xor(suma,m); sumb += __shfl_xor(sumb,m); }
    #pragma unroll
    for (int j = 0; j < 4; ++j) {
        const int m = lane + 64*j;
        if (m < NTOK_) {
            ps[wid][m] = (bf16_t)pa[j];
            if (vb) ps[wid+4][m] = (bf16_t)pb[j];
        }
    }
    const float inva = 1.0f/suma, invb = 1.0f/sumb;
    const bf16_t* vbase = qkv + (size_t)b*NTOK_*2304 + 1536 + h*HD_ + lane;
    float aa = 0.0f, ab = 0.0f;
    if (vb) {
        for (int m = 0; m < NTOK_; ++m) {
            const float vv = (float)vbase[(size_t)m*2304];
            aa += (float)ps[wid][m]*vv;
            ab += (float)ps[wid+4][m]*vv;
        }
    } else {
        for (int m = 0; m < NTOK_; ++m)
            aa += (float)ps[wid][m]*(float)vbase[(size_t)m*2304];
    }
    out[(size_t)(b*NTOK_+na)*D_ + h*HD_ + lane] = (bf16_t)(aa*inva);
    if (vb) out[(size_t)(b*NTOK_+nb)*D_ + h*HD_ + lane] = (bf16_t)(ab*invb);
}

// ---------------- head: wave per class ---------------------------------------
__global__ __launch_bounds__(256) void k_head(const float* __restrict__ zn,
        const float* __restrict__ hw, const float* __restrict__ hb,
        float* __restrict__ out)
{
    const int o = blockIdx.x*4 + (threadIdx.x >> 6);
    const int b = blockIdx.y;
    const int lane = threadIdx.x & 63;
    if (o >= NCLS_) return;
    float acc = 0.0f;
    #pragma unroll 4
    for (int k = lane; k < D_; k += 64)
        acc = fmaf(zn[b*D_+k], hw[(size_t)o*D_+k], acc);
    for (int m=32;m>0;m>>=1) acc += __shfl_xor(acc, m);
    if (lane == 0) out[b*NCLS_+o] = acc + hb[o];
}

// =============================================================================
extern "C" void kernel_launch(void* const* d_in, const int* in_sizes, int n_in,
                              void* d_out, int out_size, void* d_ws, size_t ws_size,
                              hipStream_t stream)
{
    const float* x        = (const float*)d_in[0];
    const float* patch_w  = (const float*)d_in[1];
    const float* patch_b  = (const float*)d_in[2];
    const float* cls_tok  = (const float*)d_in[3];
    const float* pos_emb  = (const float*)d_in[4];
    const float* ln1_w    = (const float*)d_in[5];
    const float* ln1_b    = (const float*)d_in[6];
    const float* qkv_w    = (const float*)d_in[7];
    const float* qkv_b    = (const float*)d_in[8];
    const float* proj_w   = (const float*)d_in[9];
    const float* proj_b   = (const float*)d_in[10];
    const float* ln2_w    = (const float*)d_in[11];
    const float* ln2_b    = (const float*)d_in[12];
    const float* fc1_w    = (const float*)d_in[13];
    const float* fc1_b    = (const float*)d_in[14];
    const float* fc2_w    = (const float*)d_in[15];
    const float* fc2_b    = (const float*)d_in[16];
    const float* gate_w   = (const float*)d_in[17];
    const float* gate_b   = (const float*)d_in[18];
    const float* exp_w1   = (const float*)d_in[19];
    const float* exp_b1   = (const float*)d_in[20];
    const float* exp_w2   = (const float*)d_in[21];
    const float* exp_b2   = (const float*)d_in[22];
    const float* norm_w   = (const float*)d_in[23];
    const float* norm_b   = (const float*)d_in[24];
    const float* head_w   = (const float*)d_in[25];
    const float* head_b   = (const float*)d_in[26];

    char* wsb = (char*)d_ws;
    size_t off_ = 0;
    auto alloc = [&](size_t nelem, size_t esz) -> void* {
        void* p = wsb + off_;
        off_ += ((nelem*esz + 255) / 256) * 256;
        return p;
    };
    float*  z      = (float*) alloc((size_t)T_*D_, 4);
    bf16_t* lnbuf  = (bf16_t*)alloc((size_t)T_*D_, 2);
    bf16_t* qkvbuf = (bf16_t*)alloc((size_t)T_*3*D_, 2);
    bf16_t* abuf   = (bf16_t*)alloc((size_t)T_*D_, 2);
    bf16_t* hid    = (bf16_t*)alloc((size_t)NSLOT_*DH_, 2);
    float*  pp     = (float*) alloc((size_t)2*T_*D_, 4);      // split-K partials (proj/fc2)
    float*  mp     = (float*) alloc((size_t)2*NSLOT_*D_, 4);  // split-K partials (moe2)
    float*  t_sc   = (float*) alloc(NSLOT_, 4);
    float*  zn     = (float*) alloc((size_t)B_*D_, 4);
    int*    t_e    = (int*)   alloc(NSLOT_, 4);
    int*    rg     = (int*)   alloc(NSLOT_, 4);
    int*    gidx   = (int*)   alloc(NSLOT_, 4);
    int*    offs   = (int*)   alloc(8, 4);
    int*    counts = (int*)   alloc(8, 4);
    const size_t n_patch = (size_t)D_*D_;
    const size_t n_qkv   = (size_t)DEPTH_*3*D_*D_;
    const size_t n_proj  = (size_t)DEPTH_*D_*D_;
    const size_t n_fc1   = (size_t)6*DH_*D_;
    const size_t n_fc2   = (size_t)6*D_*DH_;
    const size_t n_e1    = (size_t)6*NE_*DH_*D_;
    const size_t n_e2    = (size_t)6*NE_*D_*DH_;
    bf16_t* wb_patch = (bf16_t*)alloc(n_patch, 2);
    bf16_t* wb_qkv   = (bf16_t*)alloc(n_qkv, 2);
    bf16_t* wb_proj  = (bf16_t*)alloc(n_proj, 2);
    bf16_t* wb_fc1   = (bf16_t*)alloc(n_fc1, 2);
    bf16_t* wb_fc2   = (bf16_t*)alloc(n_fc2, 2);
    bf16_t* wb_e1    = (bf16_t*)alloc(n_e1, 2);
    bf16_t* wb_e2    = (bf16_t*)alloc(n_e2, 2);
    bf16_t* pbuf   = hid;      // patch staging, dead before fc1 first writes hid
    float*  pout   = mp;       // patch-proj f32 out, dead before moe2 writes mp

    // ---- weight pre-convert (f32 -> bf16), 16 elems/thread ----
    auto cvt = [&](const float* src, bf16_t* dst, size_t n){
        k_cvt<<<dim3((unsigned)((n/16 + 255)/256)), 256, 0, stream>>>(src, dst, (long)n);
    };
    cvt(patch_w, wb_patch, n_patch);
    cvt(qkv_w,   wb_qkv,   n_qkv);
    cvt(proj_w,  wb_proj,  n_proj);
    cvt(fc1_w,   wb_fc1,   n_fc1);
    cvt(fc2_w,   wb_fc2,   n_fc2);
    cvt(exp_w1,  wb_e1,    n_e1);
    cvt(exp_w2,  wb_e2,    n_e2);

    // ---- patch embedding + assemble + LN1(layer 0) ----
    k_patch_gather<<<dim3((TP_*D_+255)/256), 256, 0, stream>>>(x, pbuf);
    k_dgemm<0,0,0,0,1,0><<<dim3(D_/128, (TP_+63)/64), 256, 0, stream>>>(
        pbuf, nullptr, wb_patch, patch_b, pout, TP_, D_, D_, nullptr, nullptr);
    k_asmln<<<T_, 256, 0, stream>>>(pout, cls_tok, pos_emb, z, ln1_w, ln1_b, lnbuf);

    const int GY = (T_+63)/64;   // 25
    int di = 0, mi = 0;
    for (int i = 0; i < DEPTH_; ++i){
        // lnbuf holds LN1(z) on entry
        k_dgemm<0,0,0,1,1,0><<<dim3(3*D_/128, GY), 256, 0, stream>>>(
            lnbuf, nullptr, wb_qkv + (size_t)i*3*D_*D_, qkv_b + (size_t)i*3*D_,
            qkvbuf, T_, 3*D_, D_, nullptr, nullptr);
        k_attn<<<dim3((NTOK_+7)/8, NH_, B_), 256, 0, stream>>>(qkvbuf, abuf);
        k_dgemm<0,0,0,0,2,1><<<dim3(D_/128, GY, 2), 256, 0, stream>>>(
            abuf, nullptr, wb_proj + (size_t)i*D_*D_, nullptr,
            pp, T_, D_, D_, nullptr, nullptr);
        if (i & 1){ // MoE layers 1,3,5,7,9,11
            k_addln<1,2><<<T_, 256, 0, stream>>>(z, pp, proj_b + i*D_,
                ln2_w + i*D_, ln2_b + i*D_, lnbuf,
                gate_w + (size_t)mi*NE_*D_, gate_b + (size_t)mi*NE_, t_e, t_sc);
            k_scansc<<<1, 1024, 0, stream>>>(t_e, gidx, rg, offs, counts);
            k_dgemm<1,1,1,1,1,0><<<dim3(DH_/128, 50, NE_), 256, 0, stream>>>(
                lnbuf, gidx, wb_e1 + (size_t)mi*NE_*DH_*D_, exp_b1 + (size_t)mi*NE_*DH_,
                hid, NSLOT_, DH_, D_, offs, counts);
            k_dgemm<0,0,1,0,2,1><<<dim3(D_/128, 100, NE_), 256, 0, stream>>>(
                hid, nullptr, wb_e2 + (size_t)mi*NE_*D_*DH_, nullptr,
                mp, NSLOT_, D_, DH_, offs, counts);
            if (i + 1 < DEPTH_) {
                k_comb<1><<<T_, 256, 0, stream>>>(mp, exp_b2 + (size_t)mi*NE_*D_,
                    t_e, rg, t_sc, z, ln1_w + (i+1)*D_, ln1_b + (i+1)*D_, lnbuf);
            } else {
                k_comb<0><<<T_, 256, 0, stream>>>(mp, exp_b2 + (size_t)mi*NE_*D_,
                    t_e, rg, t_sc, z, nullptr, nullptr, nullptr);
            }
            mi++;
        } else {
            k_addln<0,2><<<T_, 256, 0, stream>>>(z, pp, proj_b + i*D_,
                ln2_w + i*D_, ln2_b + i*D_, lnbuf,
                nullptr, nullptr, nullptr, nullptr);
            k_dgemm<1,0,0,1,1,0><<<dim3(DH_/128, GY), 256, 0, stream>>>(
                lnbuf, nullptr, wb_fc1 + (size_t)di*DH_*D_, fc1_b + (size_t)di*DH_,
                hid, T_, DH_, D_, nullptr, nullptr);
            k_dgemm<0,0,0,0,2,1><<<dim3(D_/128, GY, 2), 256, 0, stream>>>(
                hid, nullptr, wb_fc2 + (size_t)di*D_*DH_, nullptr,
                pp, T_, D_, DH_, nullptr, nullptr);
            k_addln<0,2><<<T_, 256, 0, stream>>>(z, pp, fc2_b + di*D_,
                ln1_w + (i+1)*D_, ln1_b + (i+1)*D_, lnbuf,
                nullptr, nullptr, nullptr, nullptr);
            di++;
        }
    }
    // ---- final LN on cls tokens only + head ----
    k_ln<float><<<B_, 256, 0, stream>>>(z, norm_w, norm_b, zn, NTOK_);
    k_head<<<dim3((NCLS_+3)/4, B_), 256, 0, stream>>>(zn, head_w, head_b, (float*)d_out);
}

// Round 20
// 2514.132 us; speedup vs baseline: 1.0124x; 1.0023x over previous
//
#include <hip/hip_runtime.h>
#include <hip/hip_bf16.h>
#include <math.h>

#define B_     8
#define IMG_   224
#define PATCH_ 16
#define CIN_   3
#define D_     768
#define NH_    12
#define DEPTH_ 12
#define NE_    8
#define NCLS_  1000
#define DH_    3072
#define HD_    64
#define GRD_   14
#define NPAT_  196
#define NTOK_  197
#define T_     (B_*NTOK_)    /* 1576 tokens */
#define TP_    (B_*NPAT_)    /* 1568 patches */
#define NSLOT_ (T_*2)        /* 3152 (token,slot) pairs */

typedef __bf16 bf16_t;
typedef __bf16 bf16x8 __attribute__((ext_vector_type(8)));
typedef __bf16 bf16x4 __attribute__((ext_vector_type(4)));
typedef float  f32x4  __attribute__((ext_vector_type(4)));

static __device__ __forceinline__ float gelu_f(float x){
    return 0.5f * x * (1.0f + erff(x * 0.70710678118654752440f));
}

// ---------------- f32 -> bf16 bulk convert (16 elems/thread) -----------------
__global__ __launch_bounds__(256) void k_cvt(const float* __restrict__ in,
                                             bf16_t* __restrict__ out, long n){
    long i = ((long)blockIdx.x*256 + threadIdx.x)*16;
    if (i >= n) return;
    float4 a0 = *reinterpret_cast<const float4*>(in + i);
    float4 a1 = *reinterpret_cast<const float4*>(in + i + 4);
    float4 b0 = *reinterpret_cast<const float4*>(in + i + 8);
    float4 b1 = *reinterpret_cast<const float4*>(in + i + 12);
    bf16x8 h0, h1;
    h0[0]=(bf16_t)a0.x; h0[1]=(bf16_t)a0.y; h0[2]=(bf16_t)a0.z; h0[3]=(bf16_t)a0.w;
    h0[4]=(bf16_t)a1.x; h0[5]=(bf16_t)a1.y; h0[6]=(bf16_t)a1.z; h0[7]=(bf16_t)a1.w;
    h1[0]=(bf16_t)b0.x; h1[1]=(bf16_t)b0.y; h1[2]=(bf16_t)b0.z; h1[3]=(bf16_t)b0.w;
    h1[4]=(bf16_t)b1.x; h1[5]=(bf16_t)b1.y; h1[6]=(bf16_t)b1.z; h1[7]=(bf16_t)b1.w;
    *reinterpret_cast<bf16x8*>(out + i)     = h0;
    *reinterpret_cast<bf16x8*>(out + i + 8) = h1;
}

// ---------------- patch gather: x[B,3,224,224] -> pbuf[1568,768] bf16 -------
__global__ void k_patch_gather(const float* __restrict__ x, bf16_t* __restrict__ pbuf){
    int idx = blockIdx.x*256 + threadIdx.x;
    if (idx >= TP_*D_) return;
    int k  = idx % D_;
    int tp = idx / D_;
    int p  = tp % NPAT_, b = tp / NPAT_;
    int c  = k >> 8;
    int ij = k & 255;
    int i  = ij >> 4, j = ij & 15;
    int gi = p / GRD_, gj = p % GRD_;
    pbuf[idx] = (bf16_t)x[(((size_t)b*CIN_ + c)*IMG_ + gi*PATCH_ + i)*IMG_ + gj*PATCH_ + j];
}

// ---------------- unified bf16 MFMA GEMM: BK=128 single buffer ---------------
// BM=64, BN=128, BK=128, 256 threads (4 waves x 32x64 output), 48KB LDS
// (single buffer) -> 3 blk/CU. r16: halves serial K-chain for grid-limited
// GEMMs; r17: MoE-neutral; r19: proj split-K +25us.
// PARTIAL=1: raw f32 out (no bias/act) [+ ksid*M*N when KSPLIT=2].
template<int ACT, int GATHER, int MOE, int OUTBF, int KSPLIT, int PARTIAL>
__global__ __launch_bounds__(256) void k_dgemm(
    const bf16_t* __restrict__ A, const int* __restrict__ gidx,
    const bf16_t* __restrict__ W, const float* __restrict__ bias,
    void* __restrict__ Cout, int M, int N, int K,
    const int* __restrict__ moff, const int* __restrict__ mcnt)
{
    __shared__ __align__(16) bf16_t As[64*128];
    __shared__ __align__(16) bf16_t Bs[128*128];
    const int tid = threadIdx.x, lane = tid & 63, w = tid >> 6;
    int row_begin, Mhi, ksid;
    if (MOE) {
        const int e = blockIdx.z;
        const int o = moff[e], c = mcnt[e];
        const int rb = (KSPLIT == 2) ? (int)(blockIdx.y >> 1) : (int)blockIdx.y;
        ksid = (KSPLIT == 2) ? (int)(blockIdx.y & 1) : 0;
        row_begin = o + rb*64;
        Mhi = o + c;
        if (row_begin >= Mhi) return;
        W += (size_t)e*N*K;
        if (!PARTIAL) bias += (size_t)e*N;
    } else {
        row_begin = blockIdx.y*64;
        ksid = (KSPLIT == 2) ? (int)blockIdx.z : 0;
        Mhi = M;
    }
    const int bn = blockIdx.x*128;
    const int KL = K / KSPLIT;

    const bf16_t* aG[4];
    int aOff[4];
    #pragma unroll
    for (int i = 0; i < 4; ++i) {
        const int s = w*4 + i;
        const int row_l = s*4 + (lane >> 4);
        const int cc = (lane & 15) ^ (row_l & 7);
        const int gg = min(row_begin + row_l, Mhi - 1);
        const int tok = GATHER ? (gidx[gg] >> 1) : gg;
        aG[i] = A + (size_t)tok*K + ksid*KL + cc*8;
        aOff[i] = s*512;
    }
    const bf16_t* wG[8];
    int wOff[8];
    #pragma unroll
    for (int j = 0; j < 8; ++j) {
        const int s = w*8 + j;
        const int row_l = s*4 + (lane >> 4);
        const int cc = (lane & 15) ^ (row_l & 7);
        wG[j] = W + (size_t)(bn + row_l)*K + ksid*KL + cc*8;
        wOff[j] = s*512;
    }
    const int wm = (w >> 1)*32, wn = (w & 1)*64;
    const int fr = lane & 15, kg = lane >> 4;
    int offA[4][2], offB[4][4];
    #pragma unroll
    for (int ks = 0; ks < 4; ++ks) {
        #pragma unroll
        for (int t = 0; t < 2; ++t) {
            const int ra = wm + t*16 + fr;
            offA[ks][t] = ra*256 + (((ks*4 + kg) ^ (ra & 7)) << 4);
        }
        #pragma unroll
        for (int t = 0; t < 4; ++t) {
            const int rb2 = wn + t*16 + fr;
            offB[ks][t] = rb2*256 + (((ks*4 + kg) ^ (rb2 & 7)) << 4);
        }
    }

    f32x4 acc[2][4] = {};
    const int nt = KL >> 7;
    for (int t = 0; t < nt; ++t) {
        if (t) __syncthreads();            // prior reads of As/Bs complete
        #pragma unroll
        for (int i = 0; i < 4; ++i) {
            __builtin_amdgcn_global_load_lds(
                (const __attribute__((address_space(1))) void*)(aG[i]),
                (__attribute__((address_space(3))) void*)(&As[aOff[i]]), 16, 0, 0);
            aG[i] += 128;
        }
        #pragma unroll
        for (int j = 0; j < 8; ++j) {
            __builtin_amdgcn_global_load_lds(
                (const __attribute__((address_space(1))) void*)(wG[j]),
                (__attribute__((address_space(3))) void*)(&Bs[wOff[j]]), 16, 0, 0);
            wG[j] += 128;
        }
        __syncthreads();                   // drains vmcnt -> tile ready
        const char* baseA = (const char*)&As[0];
        const char* baseB = (const char*)&Bs[0];
        #pragma unroll
        for (int ks = 0; ks < 4; ++ks) {
            bf16x8 af[2], bf[4];
            #pragma unroll
            for (int t2 = 0; t2 < 2; ++t2)
                af[t2] = *reinterpret_cast<const bf16x8*>(baseA + offA[ks][t2]);
            #pragma unroll
            for (int t2 = 0; t2 < 4; ++t2)
                bf[t2] = *reinterpret_cast<const bf16x8*>(baseB + offB[ks][t2]);
            #pragma unroll
            for (int mt = 0; mt < 2; ++mt)
                #pragma unroll
                for (int nt2 = 0; nt2 < 4; ++nt2)
                    acc[mt][nt2] = __builtin_amdgcn_mfma_f32_16x16x32_bf16(
                        af[mt], bf[nt2], acc[mt][nt2], 0, 0, 0);
        }
    }
    float*  Cf = (float*)Cout + ((PARTIAL && KSPLIT == 2) ? (size_t)ksid*M*N : (size_t)0);
    bf16_t* Cb = (bf16_t*)Cout;
    const int cr = kg*4;
    #pragma unroll
    for (int nt2 = 0; nt2 < 4; ++nt2) {
        const int n = bn + wn + nt2*16 + fr;
        const float bv = PARTIAL ? 0.0f : bias[n];
        #pragma unroll
        for (int mt = 0; mt < 2; ++mt) {
            #pragma unroll
            for (int r2 = 0; r2 < 4; ++r2) {
                const int m = row_begin + wm + mt*16 + cr + r2;
                if (m < Mhi) {
                    float v = acc[mt][nt2][r2] + bv;
                    if (ACT) v = gelu_f(v);
                    if (OUTBF) Cb[(size_t)m*N + n] = (bf16_t)v;
                    else       Cf[(size_t)m*N + n] = v;
                }
            }
        }
    }
}

// ---------------- LN core (device) -------------------------------------------
struct LNOut { float y0, y1, y2; };
static __device__ __forceinline__ LNOut ln_block(float v0, float v1, float v2,
        const float* __restrict__ w, const float* __restrict__ b,
        float* red, int tid)
{
    const int wid = tid >> 6, lane = tid & 63;
    float s = v0 + v1 + v2;
    for (int m=32;m>0;m>>=1) s += __shfl_xor(s, m);
    if (lane == 0) red[wid] = s;
    __syncthreads();
    if (tid == 0) red[4] = (red[0]+red[1]+red[2]+red[3]) * (1.0f/768.0f);
    __syncthreads();
    const float mean = red[4];
    float d0 = v0-mean, d1 = v1-mean, d2 = v2-mean;
    float q = d0*d0 + d1*d1 + d2*d2;
    for (int m=32;m>0;m>>=1) q += __shfl_xor(q, m);
    if (lane == 0) red[wid] = q;
    __syncthreads();
    if (tid == 0) {
        float var = (red[0]+red[1]+red[2]+red[3]) * (1.0f/768.0f);
        red[5] = 1.0f / sqrtf(var + 1e-5f);
    }
    __syncthreads();
    const float rstd = red[5];
    LNOut o;
    o.y0 = d0*rstd*w[tid    ] + b[tid    ];
    o.y1 = d1*rstd*w[tid+256] + b[tid+256];
    o.y2 = d2*rstd*w[tid+512] + b[tid+512];
    return o;
}

// ---------------- plain LayerNorm (final) ------------------------------------
template<typename TOUT>
__global__ __launch_bounds__(256) void k_ln(const float* __restrict__ X,
        const float* __restrict__ w, const float* __restrict__ b,
        TOUT* __restrict__ Y, int in_mul)
{
    __shared__ float red[8];
    const int r = blockIdx.x, tid = threadIdx.x;
    const float* xr = X + (size_t)r*in_mul*D_;
    LNOut o = ln_block(xr[tid], xr[tid+256], xr[tid+512], w, b, red, tid);
    TOUT* yr = Y + (size_t)r*D_;
    yr[tid] = (TOUT)o.y0; yr[tid+256] = (TOUT)o.y1; yr[tid+512] = (TOUT)o.y2;
}

// -------- assemble (cls / patch-partials P0+P1+pbias + pos) + LN1(layer 0) ---
__global__ __launch_bounds__(256) void k_asmln(const float* __restrict__ pe,
        const float* __restrict__ pbias,
        const float* __restrict__ cls, const float* __restrict__ pos,
        float* __restrict__ z, const float* __restrict__ w,
        const float* __restrict__ b, bf16_t* __restrict__ Y)
{
    __shared__ float red[8];
    const int t = blockIdx.x, tid = threadIdx.x;
    const int bb = t / NTOK_, r = t % NTOK_;
    const float* pe1 = pe + (size_t)TP_*D_;
    float v[3];
    #pragma unroll
    for (int j = 0; j < 3; ++j) {
        const int n = tid + j*256;
        if (r == 0) v[j] = cls[n] + pos[n];
        else {
            const size_t pidx = ((size_t)bb*NPAT_ + (r-1))*D_ + n;
            v[j] = pe[pidx] + pe1[pidx] + pbias[n] + pos[(size_t)r*D_ + n];
        }
        z[(size_t)t*D_ + n] = v[j];
    }
    LNOut o = ln_block(v[0], v[1], v[2], w, b, red, tid);
    bf16_t* yr = Y + (size_t)t*D_;
    yr[tid] = (bf16_t)o.y0; yr[tid+256] = (bf16_t)o.y1; yr[tid+512] = (bf16_t)o.y2;
}

// -------- z += P0(+P1)+bias; LN -> Y; optional MoE gate ----------------------
template<int GATE, int NP>
__global__ __launch_bounds__(256) void k_addln(
    float* __restrict__ z, const float* __restrict__ P,
    const float* __restrict__ bias,
    const float* __restrict__ w, const float* __restrict__ b,
    bf16_t* __restrict__ Y,
    const float* __restrict__ gw, const float* __restrict__ gb,
    int* __restrict__ t_e, float* __restrict__ t_sc)
{
    __shared__ float red[8];
    __shared__ float red2[4][8];
    const int t = blockIdx.x, tid = threadIdx.x;
    const int wid = tid >> 6, lane = tid & 63;
    const float* P1 = P + (size_t)T_*D_;
    float v[3];
    #pragma unroll
    for (int j = 0; j < 3; ++j) {
        const int n = tid + j*256;
        float nv = z[(size_t)t*D_+n] + P[(size_t)t*D_+n] + bias[n];
        if (NP == 2) nv += P1[(size_t)t*D_+n];
        z[(size_t)t*D_+n] = nv;
        v[j] = nv;
    }
    LNOut o = ln_block(v[0], v[1], v[2], w, b, red, tid);
    bf16_t* yr = Y + (size_t)t*D_;
    yr[tid] = (bf16_t)o.y0; yr[tid+256] = (bf16_t)o.y1; yr[tid+512] = (bf16_t)o.y2;
    if (GATE) {
        float p[NE_];
        #pragma unroll
        for (int e = 0; e < NE_; ++e)
            p[e] = o.y0*gw[e*D_+tid] + o.y1*gw[e*D_+tid+256] + o.y2*gw[e*D_+tid+512];
        #pragma unroll
        for (int e = 0; e < NE_; ++e)
            for (int m=32;m>0;m>>=1) p[e] += __shfl_xor(p[e], m);
        if (lane == 0)
            #pragma unroll
            for (int e = 0; e < NE_; ++e) red2[wid][e] = p[e];
        __syncthreads();
        if (tid == 0) {
            float l[NE_];
            #pragma unroll
            for (int e = 0; e < NE_; ++e)
                l[e] = red2[0][e]+red2[1][e]+red2[2][e]+red2[3][e] + gb[e];
            int i0 = 0;
            for (int e = 1; e < NE_; ++e) if (l[e] > l[i0]) i0 = e;
            int i1 = -1;
            for (int e = 0; e < NE_; ++e) if (e != i0 && (i1 < 0 || l[e] > l[i1])) i1 = e;
            float e1 = __expf(l[i1] - l[i0]);
            float s = 1.0f + e1;
            t_e[t*2]   = i0;   t_e[t*2+1]  = i1;
            t_sc[t*2]  = 1.0f/s; t_sc[t*2+1] = e1/s;
        }
    }
}

// ---------------- scan+scatter: one block ------------------------------------
__global__ __launch_bounds__(1024) void k_scansc(const int* __restrict__ t_e,
        int* __restrict__ gidx, int* __restrict__ rg,
        int* __restrict__ offs, int* __restrict__ counts)
{
    __shared__ int h[NE_], o[NE_], c2[NE_];
    const int tid = threadIdx.x;
    if (tid < NE_) h[tid] = 0;
    __syncthreads();
    for (int id = tid; id < NSLOT_; id += 1024) atomicAdd(&h[t_e[id]], 1);
    __syncthreads();
    if (tid == 0) {
        int s = 0;
        for (int e = 0; e < NE_; ++e) { o[e] = s; s += h[e]; c2[e] = 0; }
    }
    __syncthreads();
    if (tid < NE_) { offs[tid] = o[tid]; counts[tid] = h[tid]; }
    for (int id = tid; id < NSLOT_; id += 1024) {
        int e = t_e[id];
        int pos = atomicAdd(&c2[e], 1);
        int g = o[e] + pos;
        gidx[g] = id;
        rg[id] = g;
    }
}

// -------- MoE combine from 2 partials (+expert bias); optional next-LN -------
template<int LN>
__global__ __launch_bounds__(256) void k_comb(
    const float* __restrict__ mp, const float* __restrict__ b2,
    const int* __restrict__ t_e, const int* __restrict__ rg,
    const float* __restrict__ t_sc, float* __restrict__ z,
    const float* __restrict__ w, const float* __restrict__ b,
    bf16_t* __restrict__ Y)
{
    __shared__ float red[8];
    const int t = blockIdx.x, tid = threadIdx.x;
    const int g0 = rg[2*t], g1 = rg[2*t+1];
    const int e0 = t_e[2*t], e1 = t_e[2*t+1];
    const float s0 = t_sc[2*t], s1 = t_sc[2*t+1];
    const float* mp1 = mp + (size_t)NSLOT_*D_;
    float v[3];
    #pragma unroll
    for (int j = 0; j < 3; ++j) {
        const int n = tid + j*256;
        float y0 = mp[(size_t)g0*D_+n] + mp1[(size_t)g0*D_+n] + b2[(size_t)e0*D_+n];
        float y1 = mp[(size_t)g1*D_+n] + mp1[(size_t)g1*D_+n] + b2[(size_t)e1*D_+n];
        float nv = z[(size_t)t*D_+n] + s0*y0 + s1*y1;
        z[(size_t)t*D_+n] = nv;
        v[j] = nv;
    }
    if (LN) {
        LNOut o = ln_block(v[0], v[1], v[2], w, b, red, tid);
        bf16_t* yr = Y + (size_t)t*D_;
        yr[tid] = (bf16_t)o.y0; yr[tid+256] = (bf16_t)o.y1; yr[tid+512] = (bf16_t)o.y2;
    }
}

// ---------------- attention: wave-per-2-queries, barrier-free ----------------
__global__ __launch_bounds__(256) void k_attn(const bf16_t* __restrict__ qkv,
                                              bf16_t* __restrict__ out)
{
    __shared__ bf16_t Kl[NTOK_*68];
    __shared__ float  qs[8][64];
    __shared__ bf16_t ps[8][200];
    const int qb = blockIdx.x*8;
    const int h = blockIdx.y, b = blockIdx.z;
    const int tid = threadIdx.x, lane = tid & 63, wid = tid >> 6;
    for (int id = tid; id < NTOK_*8; id += 256) {
        const int m = id >> 3, c = id & 7;
        bf16x8 v = *reinterpret_cast<const bf16x8*>(
            qkv + (size_t)(b*NTOK_+m)*2304 + 768 + h*HD_ + c*8);
        bf16x4 lo = {v[0],v[1],v[2],v[3]}, hi = {v[4],v[5],v[6],v[7]};
        *reinterpret_cast<bf16x4*>(&Kl[m*68 + c*8    ]) = lo;
        *reinterpret_cast<bf16x4*>(&Kl[m*68 + c*8 + 4]) = hi;
    }
    for (int id = tid; id < 512; id += 256) {
        const int qq = id >> 6, d = id & 63;
        const int n = qb + qq;
        qs[qq][d] = (n < NTOK_) ? (float)qkv[(size_t)(b*NTOK_+n)*2304 + h*HD_ + d] : 0.0f;
    }
    __syncthreads();
    const int na = qb + wid, nb = qb + wid + 4;
    const bool va = na < NTOK_, vb = nb < NTOK_;
    if (!va) return;
    float sa[4] = {0,0,0,0}, sb[4] = {0,0,0,0};
    for (int d = 0; d < HD_; d += 4) {
        const f32x4 qa = *reinterpret_cast<const f32x4*>(&qs[wid][d]);
        const f32x4 qv = *reinterpret_cast<const f32x4*>(&qs[wid+4][d]);
        #pragma unroll
        for (int j = 0; j < 4; ++j) {
            const int m = lane + 64*j;
            const int mc = m < NTOK_ ? m : NTOK_-1;
            bf16x4 kv = *reinterpret_cast<const bf16x4*>(&Kl[mc*68 + d]);
            float k0=(float)kv[0], k1=(float)kv[1], k2=(float)kv[2], k3=(float)kv[3];
            sa[j] += qa[0]*k0 + qa[1]*k1 + qa[2]*k2 + qa[3]*k3;
            sb[j] += qv[0]*k0 + qv[1]*k1 + qv[2]*k2 + qv[3]*k3;
        }
    }
    #pragma unroll
    for (int j = 0; j < 4; ++j) {
        const bool ok = (lane + 64*j) < NTOK_;
        sa[j] = ok ? sa[j]*0.125f : -3.0e38f;
        sb[j] = ok ? sb[j]*0.125f : -3.0e38f;
    }
    float mxa = fmaxf(fmaxf(sa[0],sa[1]), fmaxf(sa[2],sa[3]));
    float mxb = fmaxf(fmaxf(sb[0],sb[1]), fmaxf(sb[2],sb[3]));
    for (int m=32;m>0;m>>=1) { mxa = fmaxf(mxa, __shfl_xor(mxa,m)); mxb = fmaxf(mxb, __shfl_xor(mxb,m)); }
    float pa[4], pb[4], suma = 0.0f, sumb = 0.0f;
    #pragma unroll
    for (int j = 0; j < 4; ++j) {
        pa[j] = __expf(sa[j]-mxa); suma += pa[j];
        pb[j] = __expf(sb[j]-mxb); sumb += pb[j];
    }
    for (int m=32;m>0;m>>=1) { suma += __shfl_xor(suma,m); sumb += __shfl_xor(sumb,m); }
    #pragma unroll
    for (int j = 0; j < 4; ++j) {
        const int m = lane + 64*j;
        if (m < NTOK_) {
            ps[wid][m] = (bf16_t)pa[j];
            if (vb) ps[wid+4][m] = (bf16_t)pb[j];
        }
    }
    const float inva = 1.0f/suma, invb = 1.0f/sumb;
    const bf16_t* vbase = qkv + (size_t)b*NTOK_*2304 + 1536 + h*HD_ + lane;
    float aa = 0.0f, ab = 0.0f;
    if (vb) {
        for (int m = 0; m < NTOK_; ++m) {
            const float vv = (float)vbase[(size_t)m*2304];
            aa += (float)ps[wid][m]*vv;
            ab += (float)ps[wid+4][m]*vv;
        }
    } else {
        for (int m = 0; m < NTOK_; ++m)
            aa += (float)ps[wid][m]*(float)vbase[(size_t)m*2304];
    }
    out[(size_t)(b*NTOK_+na)*D_ + h*HD_ + lane] = (bf16_t)(aa*inva);
    if (vb) out[(size_t)(b*NTOK_+nb)*D_ + h*HD_ + lane] = (bf16_t)(ab*invb);
}

// ---------------- head: wave per class ---------------------------------------
__global__ __launch_bounds__(256) void k_head(const float* __restrict__ zn,
        const float* __restrict__ hw, const float* __restrict__ hb,
        float* __restrict__ out)
{
    const int o = blockIdx.x*4 + (threadIdx.x >> 6);
    const int b = blockIdx.y;
    const int lane = threadIdx.x & 63;
    if (o >= NCLS_) return;
    float acc = 0.0f;
    #pragma unroll 4
    for (int k = lane; k < D_; k += 64)
        acc = fmaf(zn[b*D_+k], hw[(size_t)o*D_+k], acc);
    for (int m=32;m>0;m>>=1) acc += __shfl_xor(acc, m);
    if (lane == 0) out[b*NCLS_+o] = acc + hb[o];
}

// =============================================================================
extern "C" void kernel_launch(void* const* d_in, const int* in_sizes, int n_in,
                              void* d_out, int out_size, void* d_ws, size_t ws_size,
                              hipStream_t stream)
{
    const float* x        = (const float*)d_in[0];
    const float* patch_w  = (const float*)d_in[1];
    const float* patch_b  = (const float*)d_in[2];
    const float* cls_tok  = (const float*)d_in[3];
    const float* pos_emb  = (const float*)d_in[4];
    const float* ln1_w    = (const float*)d_in[5];
    const float* ln1_b    = (const float*)d_in[6];
    const float* qkv_w    = (const float*)d_in[7];
    const float* qkv_b    = (const float*)d_in[8];
    const float* proj_w   = (const float*)d_in[9];
    const float* proj_b   = (const float*)d_in[10];
    const float* ln2_w    = (const float*)d_in[11];
    const float* ln2_b    = (const float*)d_in[12];
    const float* fc1_w    = (const float*)d_in[13];
    const float* fc1_b    = (const float*)d_in[14];
    const float* fc2_w    = (const float*)d_in[15];
    const float* fc2_b    = (const float*)d_in[16];
    const float* gate_w   = (const float*)d_in[17];
    const float* gate_b   = (const float*)d_in[18];
    const float* exp_w1   = (const float*)d_in[19];
    const float* exp_b1   = (const float*)d_in[20];
    const float* exp_w2   = (const float*)d_in[21];
    const float* exp_b2   = (const float*)d_in[22];
    const float* norm_w   = (const float*)d_in[23];
    const float* norm_b   = (const float*)d_in[24];
    const float* head_w   = (const float*)d_in[25];
    const float* head_b   = (const float*)d_in[26];

    char* wsb = (char*)d_ws;
    size_t off_ = 0;
    auto alloc = [&](size_t nelem, size_t esz) -> void* {
        void* p = wsb + off_;
        off_ += ((nelem*esz + 255) / 256) * 256;
        return p;
    };
    float*  z      = (float*) alloc((size_t)T_*D_, 4);
    bf16_t* lnbuf  = (bf16_t*)alloc((size_t)T_*D_, 2);
    bf16_t* qkvbuf = (bf16_t*)alloc((size_t)T_*3*D_, 2);
    bf16_t* abuf   = (bf16_t*)alloc((size_t)T_*D_, 2);
    bf16_t* hid    = (bf16_t*)alloc((size_t)NSLOT_*DH_, 2);
    float*  pp     = (float*) alloc((size_t)2*T_*D_, 4);      // split-K partials (proj/fc2)
    float*  mp     = (float*) alloc((size_t)2*NSLOT_*D_, 4);  // split-K partials (moe2/patch)
    float*  t_sc   = (float*) alloc(NSLOT_, 4);
    float*  zn     = (float*) alloc((size_t)B_*D_, 4);
    int*    t_e    = (int*)   alloc(NSLOT_, 4);
    int*    rg     = (int*)   alloc(NSLOT_, 4);
    int*    gidx   = (int*)   alloc(NSLOT_, 4);
    int*    offs   = (int*)   alloc(8, 4);
    int*    counts = (int*)   alloc(8, 4);
    const size_t n_patch = (size_t)D_*D_;
    const size_t n_qkv   = (size_t)DEPTH_*3*D_*D_;
    const size_t n_proj  = (size_t)DEPTH_*D_*D_;
    const size_t n_fc1   = (size_t)6*DH_*D_;
    const size_t n_fc2   = (size_t)6*D_*DH_;
    const size_t n_e1    = (size_t)6*NE_*DH_*D_;
    const size_t n_e2    = (size_t)6*NE_*D_*DH_;
    bf16_t* wb_patch = (bf16_t*)alloc(n_patch, 2);
    bf16_t* wb_qkv   = (bf16_t*)alloc(n_qkv, 2);
    bf16_t* wb_proj  = (bf16_t*)alloc(n_proj, 2);
    bf16_t* wb_fc1   = (bf16_t*)alloc(n_fc1, 2);
    bf16_t* wb_fc2   = (bf16_t*)alloc(n_fc2, 2);
    bf16_t* wb_e1    = (bf16_t*)alloc(n_e1, 2);
    bf16_t* wb_e2    = (bf16_t*)alloc(n_e2, 2);
    bf16_t* pbuf   = hid;      // patch staging, dead before fc1 first writes hid
    float*  pout   = mp;       // patch-proj f32 partials (2 x TP_*D_ fits in mp)

    // ---- weight pre-convert (f32 -> bf16), 16 elems/thread ----
    auto cvt = [&](const float* src, bf16_t* dst, size_t n){
        k_cvt<<<dim3((unsigned)((n/16 + 255)/256)), 256, 0, stream>>>(src, dst, (long)n);
    };
    cvt(patch_w, wb_patch, n_patch);
    cvt(qkv_w,   wb_qkv,   n_qkv);
    cvt(proj_w,  wb_proj,  n_proj);
    cvt(fc1_w,   wb_fc1,   n_fc1);
    cvt(fc2_w,   wb_fc2,   n_fc2);
    cvt(exp_w1,  wb_e1,    n_e1);
    cvt(exp_w2,  wb_e2,    n_e2);

    // ---- patch embedding (split-K x2, partials summed in k_asmln) ----
    k_patch_gather<<<dim3((TP_*D_+255)/256), 256, 0, stream>>>(x, pbuf);
    k_dgemm<0,0,0,0,2,1><<<dim3(D_/128, (TP_+63)/64, 2), 256, 0, stream>>>(
        pbuf, nullptr, wb_patch, nullptr, pout, TP_, D_, D_, nullptr, nullptr);
    k_asmln<<<T_, 256, 0, stream>>>(pout, patch_b, cls_tok, pos_emb,
                                    z, ln1_w, ln1_b, lnbuf);

    const int GY = (T_+63)/64;   // 25
    int di = 0, mi = 0;
    for (int i = 0; i < DEPTH_; ++i){
        // lnbuf holds LN1(z) on entry
        k_dgemm<0,0,0,1,1,0><<<dim3(3*D_/128, GY), 256, 0, stream>>>(
            lnbuf, nullptr, wb_qkv + (size_t)i*3*D_*D_, qkv_b + (size_t)i*3*D_,
            qkvbuf, T_, 3*D_, D_, nullptr, nullptr);
        k_attn<<<dim3((NTOK_+7)/8, NH_, B_), 256, 0, stream>>>(qkvbuf, abuf);
        k_dgemm<0,0,0,0,2,1><<<dim3(D_/128, GY, 2), 256, 0, stream>>>(
            abuf, nullptr, wb_proj + (size_t)i*D_*D_, nullptr,
            pp, T_, D_, D_, nullptr, nullptr);
        if (i & 1){ // MoE layers 1,3,5,7,9,11
            k_addln<1,2><<<T_, 256, 0, stream>>>(z, pp, proj_b + i*D_,
                ln2_w + i*D_, ln2_b + i*D_, lnbuf,
                gate_w + (size_t)mi*NE_*D_, gate_b + (size_t)mi*NE_, t_e, t_sc);
            k_scansc<<<1, 1024, 0, stream>>>(t_e, gidx, rg, offs, counts);
            k_dgemm<1,1,1,1,1,0><<<dim3(DH_/128, 50, NE_), 256, 0, stream>>>(
                lnbuf, gidx, wb_e1 + (size_t)mi*NE_*DH_*D_, exp_b1 + (size_t)mi*NE_*DH_,
                hid, NSLOT_, DH_, D_, offs, counts);
            k_dgemm<0,0,1,0,2,1><<<dim3(D_/128, 100, NE_), 256, 0, stream>>>(
                hid, nullptr, wb_e2 + (size_t)mi*NE_*D_*DH_, nullptr,
                mp, NSLOT_, D_, DH_, offs, counts);
            if (i + 1 < DEPTH_) {
                k_comb<1><<<T_, 256, 0, stream>>>(mp, exp_b2 + (size_t)mi*NE_*D_,
                    t_e, rg, t_sc, z, ln1_w + (i+1)*D_, ln1_b + (i+1)*D_, lnbuf);
            } else {
                k_comb<0><<<T_, 256, 0, stream>>>(mp, exp_b2 + (size_t)mi*NE_*D_,
                    t_e, rg, t_sc, z, nullptr, nullptr, nullptr);
            }
            mi++;
        } else {
            k_addln<0,2><<<T_, 256, 0, stream>>>(z, pp, proj_b + i*D_,
                ln2_w + i*D_, ln2_b + i*D_, lnbuf,
                nullptr, nullptr, nullptr, nullptr);
            k_dgemm<1,0,0,1,1,0><<<dim3(DH_/128, GY), 256, 0, stream>>>(
                lnbuf, nullptr, wb_fc1 + (size_t)di*DH_*D_, fc1_b + (size_t)di*DH_,
                hid, T_, DH_, D_, nullptr, nullptr);
            k_dgemm<0,0,0,0,2,1><<<dim3(D_/128, GY, 2), 256, 0, stream>>>(
                hid, nullptr, wb_fc2 + (size_t)di*D_*DH_, nullptr,
                pp, T_, D_, DH_, nullptr, nullptr);
            k_addln<0,2><<<T_, 256, 0, stream>>>(z, pp, fc2_b + di*D_,
                ln1_w + (i+1)*D_, ln1_b + (i+1)*D_, lnbuf,
                nullptr, nullptr, nullptr, nullptr);
            di++;
        }
    }
    // ---- final LN on cls tokens only + head ----
    k_ln<float><<<B_, 256, 0, stream>>>(z, norm_w, norm_b, zn, NTOK_);
    k_head<<<dim3((NCLS_+3)/4, B_), 256, 0, stream>>>(zn, head_w, head_b, (float*)d_out);
}